// Round 2
// baseline (272.753 us; speedup 1.0000x reference)
//
#include <hip/hip_runtime.h>
#include <hip/hip_bf16.h>
#include <math.h>

#define D_MODEL 1024
#define NHEADS  16
#define HDIM    64
#define BATCH   4
#define SEQ     2048

typedef __attribute__((ext_vector_type(8))) short bf16x8;
typedef __attribute__((ext_vector_type(4))) float f32x4;

#if __has_builtin(__builtin_amdgcn_exp2f)
#define EXP2(x) __builtin_amdgcn_exp2f(x)
#else
#define EXP2(x) exp2f(x)
#endif

__device__ __forceinline__ unsigned short f2bf(float f) {
  union { float f; unsigned u; } v; v.f = f;
  unsigned r = v.u + 0x7FFFu + ((v.u >> 16) & 1u);   // RNE
  return (unsigned short)(r >> 16);
}

__device__ __forceinline__ void load_lds16(const unsigned short* g, unsigned short* l) {
  __builtin_amdgcn_global_load_lds(
      (const __attribute__((address_space(1))) unsigned int*)g,
      (__attribute__((address_space(3))) unsigned int*)l, 16, 0, 0);
}

// ---- pre-pass: fp32 -> bf16 cast (x) ----
__global__ __launch_bounds__(256) void cast_kernel(
    const float* __restrict__ in, unsigned short* __restrict__ out)
{
  const int idx = (blockIdx.x * 256 + threadIdx.x) * 8;
  float4 a = *(const float4*)&in[idx];
  float4 b = *(const float4*)&in[idx + 4];
  alignas(16) unsigned short t[8] = {
    f2bf(a.x), f2bf(a.y), f2bf(a.z), f2bf(a.w),
    f2bf(b.x), f2bf(b.y), f2bf(b.z), f2bf(b.w)};
  *(uint4*)&out[idx] = *(uint4*)t;
}

// ---- pre-pass: W [1024][N] fp32 -> WT [N][1024] bf16 ----
__global__ __launch_bounds__(256) void transpose_cast(
    const float* __restrict__ W, unsigned short* __restrict__ WT, int N)
{
  __shared__ float t[64][65];
  const int k0 = blockIdx.y * 64, n0 = blockIdx.x * 64;
  const int tid = threadIdx.x;
  const int r = tid >> 2, c0 = (tid & 3) * 16;
  #pragma unroll
  for (int i = 0; i < 16; i += 4) {
    float4 f = *(const float4*)&W[(size_t)(k0 + r) * N + n0 + c0 + i];
    t[r][c0+i] = f.x; t[r][c0+i+1] = f.y; t[r][c0+i+2] = f.z; t[r][c0+i+3] = f.w;
  }
  __syncthreads();
  #pragma unroll
  for (int i = 0; i < 16; i += 4) {
    alignas(8) unsigned short s[4] = {
      f2bf(t[c0+i][r]), f2bf(t[c0+i+1][r]), f2bf(t[c0+i+2][r]), f2bf(t[c0+i+3][r])};
    *(uint2*)&WT[(size_t)(n0 + r) * 1024 + k0 + c0 + i] = *(uint2*)s;
  }
}

#define BARRIER __builtin_amdgcn_s_barrier()
#define FENCE   asm volatile("" ::: "memory")
#define LGKM0   do { asm volatile("s_waitcnt lgkmcnt(0)" ::: "memory"); \
                     __builtin_amdgcn_sched_barrier(0); } while (0)

// ---- 128x256-tile fine-phased GEMM (unchanged from round 1) ----
template<int MODE>
__global__ __launch_bounds__(512, 2) void gemm8p(
    const unsigned short* __restrict__ A,
    const unsigned short* __restrict__ Bt,
    const float* __restrict__ bias,
    unsigned short* __restrict__ Qb, unsigned short* __restrict__ Kb,
    unsigned short* __restrict__ Vb, float* __restrict__ Out)
{
  constexpr int N  = (MODE == 0) ? 3 * D_MODEL : D_MODEL;
  constexpr int NT = D_MODEL / 64;                 // 16 K-tiles
  const int bn = blockIdx.x * 256;
  const int bm = blockIdx.y * 128;
  const int tid  = threadIdx.x;
  const int lane = tid & 63;
  const int w    = tid >> 6;
  const int quad = lane >> 4;
  const int l16  = lane & 15;
  const int wr = w >> 2, wc = w & 3;

  __shared__ __align__(16) unsigned short lds[49152];   // 96 KiB

  const int srow = lane >> 3;
  const int scol = ((lane & 7) ^ srow) * 8;
  const unsigned short* __restrict__ Ag = A  + (size_t)(bm + w*8 + srow) * D_MODEL + scol;
  const unsigned short* __restrict__ Bg = Bt + (size_t)(bn + w*8 + srow) * D_MODEL + scol;
  const int xs = (l16 & 7) * 8;

  f32x4 acc[4][4] = {};

  auto stageA = [&](int buf, int t2) {
    unsigned short* d = &lds[buf*8192 + w*512];
    const unsigned short* g = Ag + t2*64;
    load_lds16(g,                      d);
    load_lds16(g + (size_t)64*D_MODEL, d + 4096);
  };
  auto stageB = [&](int buf, int t2) {
    unsigned short* d = &lds[16384 + buf*16384 + w*512];
    const unsigned short* g = Bg + t2*64;
    #pragma unroll
    for (int c = 0; c < 4; c++)
      load_lds16(g + (size_t)c*64*D_MODEL, d + c*4096);
  };
  auto rdA = [&](int buf, int mi, int kk) {
    return *(const bf16x8*)&lds[buf*8192 +
        (wr*64 + mi*16 + l16)*64 + (((kk*4 + quad)*8) ^ xs)];
  };
  auto rdB = [&](int buf, int ni, int kk) {
    return *(const bf16x8*)&lds[16384 + buf*16384 +
        (wc*64 + ni*16 + l16)*64 + (((kk*4 + quad)*8) ^ xs)];
  };

  stageB(0, 0); stageA(0, 0);
  stageB(1, 1); stageA(1, 1);
  asm volatile("s_waitcnt vmcnt(6)" ::: "memory");
  BARRIER;
  FENCE;

  #pragma unroll 2
  for (int t = 0; t < NT; ++t) {
    const int cur  = t & 1;
    const bool pre = (t + 2 < NT);
    bf16x8 a0[2][2], a1[2][2], b0[2][2], b1[2][2];

    // phase 0
    #pragma unroll
    for (int kk = 0; kk < 2; kk++)
      #pragma unroll
      for (int i = 0; i < 2; i++) { a0[i][kk] = rdA(cur, i, kk); b0[i][kk] = rdB(cur, i, kk); }
    BARRIER; LGKM0;
    __builtin_amdgcn_s_setprio(1);
    #pragma unroll
    for (int kk = 0; kk < 2; kk++)
      #pragma unroll
      for (int mi = 0; mi < 2; mi++)
        #pragma unroll
        for (int ni = 0; ni < 2; ni++)
          acc[mi][ni] = __builtin_amdgcn_mfma_f32_16x16x32_bf16(a0[mi][kk], b0[ni][kk], acc[mi][ni], 0, 0, 0);
    __builtin_amdgcn_s_setprio(0);
    BARRIER;

    // phase 1
    #pragma unroll
    for (int kk = 0; kk < 2; kk++)
      #pragma unroll
      for (int i = 0; i < 2; i++) b1[i][kk] = rdB(cur, 2 + i, kk);
    BARRIER; LGKM0;
    __builtin_amdgcn_s_setprio(1);
    #pragma unroll
    for (int kk = 0; kk < 2; kk++)
      #pragma unroll
      for (int mi = 0; mi < 2; mi++)
        #pragma unroll
        for (int ni = 0; ni < 2; ni++)
          acc[mi][2+ni] = __builtin_amdgcn_mfma_f32_16x16x32_bf16(a0[mi][kk], b1[ni][kk], acc[mi][2+ni], 0, 0, 0);
    __builtin_amdgcn_s_setprio(0);
    BARRIER;

    // phase 2
    #pragma unroll
    for (int kk = 0; kk < 2; kk++)
      #pragma unroll
      for (int i = 0; i < 2; i++) a1[i][kk] = rdA(cur, 2 + i, kk);
    if (pre) stageB(cur, t + 2);
    BARRIER; LGKM0;
    __builtin_amdgcn_s_setprio(1);
    #pragma unroll
    for (int kk = 0; kk < 2; kk++)
      #pragma unroll
      for (int mi = 0; mi < 2; mi++)
        #pragma unroll
        for (int ni = 0; ni < 2; ni++)
          acc[2+mi][ni] = __builtin_amdgcn_mfma_f32_16x16x32_bf16(a1[mi][kk], b0[ni][kk], acc[2+mi][ni], 0, 0, 0);
    __builtin_amdgcn_s_setprio(0);
    BARRIER;

    // phase 3
    if (pre) {
      stageA(cur, t + 2);
      asm volatile("s_waitcnt vmcnt(6)" ::: "memory");
    } else {
      asm volatile("s_waitcnt vmcnt(0)" ::: "memory");
    }
    BARRIER;
    FENCE;
    __builtin_amdgcn_s_setprio(1);
    #pragma unroll
    for (int kk = 0; kk < 2; kk++)
      #pragma unroll
      for (int mi = 0; mi < 2; mi++)
        #pragma unroll
        for (int ni = 0; ni < 2; ni++)
          acc[2+mi][2+ni] = __builtin_amdgcn_mfma_f32_16x16x32_bf16(a1[mi][kk], b1[ni][kk], acc[2+mi][2+ni], 0, 0, 0);
    __builtin_amdgcn_s_setprio(0);
    BARRIER;
  }

  const int b   = bm >> 11;
  const int tl0 = (bm & (SEQ - 1));
  #pragma unroll
  for (int ni = 0; ni < 4; ni++) {
    const int n = bn + wc*64 + ni*16 + l16;
    const float bv = bias[n];
    #pragma unroll
    for (int mi = 0; mi < 4; mi++) {
      const int t0 = tl0 + wr*64 + mi*16 + quad*4;
      if (MODE == 0) {
        const int which = n >> 10;
        const int c = n & 1023;
        const int h = c >> 6, hd = c & 63;
        const size_t bhb = ((size_t)(b*NHEADS + h)) * (SEQ*HDIM);
        if (which == 2) {
          alignas(8) unsigned short pk[4];
          #pragma unroll
          for (int r = 0; r < 4; r++) pk[r] = f2bf(acc[mi][ni][r] + bv);
          *(uint2*)&Vb[bhb + (size_t)hd*SEQ + t0] = *(uint2*)pk;
        } else if (which == 0) {
          #pragma unroll
          for (int r = 0; r < 4; r++)
            Qb[bhb + (size_t)(t0 + r)*HDIM + hd] = f2bf((acc[mi][ni][r] + bv) * 0.18033688f);
        } else {
          #pragma unroll
          for (int r = 0; r < 4; r++)
            Kb[bhb + (size_t)(t0 + r)*HDIM + hd] = f2bf(acc[mi][ni][r] + bv);
        }
      } else {
        const int m = bm + wr*64 + mi*16 + quad*4;
        #pragma unroll
        for (int r = 0; r < 4; r++)
          Out[(size_t)(m + r) * N + n] = acc[mi][ni][r] + bv;
      }
    }
  }
}

// Flash attention v9: one 128-row q-tile per block (grid 64x16 -> 4 blk/CU),
// T2 XOR-swizzle on Ks/Vs (pre-swizzled global source for global_load_lds,
// same XOR on ds_read side), T5 setprio around MFMA clusters.
__global__ __launch_bounds__(256) void attn_kernel(
    const unsigned short* __restrict__ Qb,
    const unsigned short* __restrict__ Kb,
    const unsigned short* __restrict__ Vt,
    unsigned short* __restrict__ Yb)
{
  const int bh   = blockIdx.x;
  const int qt   = blockIdx.y;                 // q-tile index 0..15 (128 rows)
  const int tid  = threadIdx.x;
  const int wave = tid >> 6;
  const int lane = tid & 63;
  const int quad = lane >> 4;
  const int l16  = lane & 15;

  __shared__ __align__(16) unsigned short Ks[64 * 64];      // [key][hd], XOR-swz
  __shared__ __align__(16) unsigned short Vs[64 * 64];      // [hd][key], XOR-swz
  __shared__ __align__(16) unsigned short Pl[8][16][72];    // per-strip P (bf16)

  const unsigned short* __restrict__ qb_ = Qb + (size_t)bh * (SEQ*HDIM);
  const unsigned short* __restrict__ kb_ = Kb + (size_t)bh * (SEQ*HDIM);
  const unsigned short* __restrict__ vb_ = Vt + (size_t)bh * (SEQ*HDIM);
  const int h = bh & (NHEADS - 1);
  const int b = bh >> 4;

  const short ob = (short)0x3F80;    // bf16 1.0
  const bf16x8 ones = {ob,ob,ob,ob,ob,ob,ob,ob};

  // staging geometry: LDS dest is linear (wave slice + lane*16B);
  // swizzle is applied to the per-lane GLOBAL column (rule 21).
  const int srow = lane >> 3;                        // 0..7 within 8-row slice
  const int scolswz = ((lane & 7) ^ srow) * 8;       // swizzled 16B slot
  const int krow0 = wave * 16 + srow;                // key-row base (K), hd-row base (V)
  const int xs = (l16 & 7) * 8;                      // read-side XOR (elems)

  const int ntiles = 2 * qt + 2;
  const int qs0 = qt * 128 + wave * 32;
  const int myLast = 2 * qt + (wave >> 1);           // last tile this wave needs

  bf16x8 qf[2][2];
  #pragma unroll
  for (int t = 0; t < 2; t++)
    #pragma unroll
    for (int kk = 0; kk < 2; kk++)
      qf[t][kk] = *(const bf16x8*)(qb_ + (qs0 + t*16 + l16)*HDIM + kk*32 + quad*8);

  f32x4 acc[2][4] = {};
  float lrow[2][4] = {};

  for (int it = 0; it < ntiles; it++) {
    const int kb = it * 64;

    // ---- stage K tile [key][hd] and V^T tile [hd][key], swizzled source ----
    #pragma unroll
    for (int j = 0; j < 2; j++)
      load_lds16(kb_ + (size_t)(kb + krow0 + j*8)*HDIM + scolswz, &Ks[wave*1024 + j*512]);
    #pragma unroll
    for (int j = 0; j < 2; j++)
      load_lds16(vb_ + (size_t)(krow0 + j*8)*SEQ + kb + scolswz, &Vs[(wave*16 + j*8)*64]);
    __syncthreads();

    if (it <= myLast) {
      // ---- S for both strips (K-frag shared) ----
      f32x4 sfr[4] = {}, sfr1[4] = {};
      __builtin_amdgcn_s_setprio(1);
      #pragma unroll
      for (int kk = 0; kk < 2; kk++)
        #pragma unroll
        for (int nf = 0; nf < 4; nf++) {
          const bf16x8 kf = *(const bf16x8*)&Ks[(nf*16 + l16)*64 + ((kk*32 + quad*8) ^ xs)];
          sfr[nf]  = __builtin_amdgcn_mfma_f32_16x16x32_bf16(qf[0][kk], kf, sfr[nf], 0, 0, 0);
          sfr1[nf] = __builtin_amdgcn_mfma_f32_16x16x32_bf16(qf[1][kk], kf, sfr1[nf], 0, 0, 0);
        }
      __builtin_amdgcn_s_setprio(0);

      // ---- causal mask on this wave's diagonal tile only ----
      if (it == myLast) {
        #pragma unroll
        for (int nf = 0; nf < 4; nf++) {
          const int kcol = kb + nf*16 + l16;
          #pragma unroll
          for (int r = 0; r < 4; r++) {
            sfr[nf][r]  = (kcol > qs0 + quad*4 + r)      ? -INFINITY : sfr[nf][r];
            sfr1[nf][r] = (kcol > qs0 + 16 + quad*4 + r) ? -INFINITY : sfr1[nf][r];
          }
        }
      }

      // ---- P = exp2(S) -> per-wave LDS bf16 (C-layout -> A-layout) ----
      #pragma unroll
      for (int nf = 0; nf < 4; nf++)
        #pragma unroll
        for (int r = 0; r < 4; r++) {
          Pl[wave*2 + 0][quad*4 + r][nf*16 + l16] = f2bf(EXP2(sfr[nf][r]));
          Pl[wave*2 + 1][quad*4 + r][nf*16 + l16] = f2bf(EXP2(sfr1[nf][r]));
        }

      // ---- PV for both strips (V-frags from LDS, swizzled) ----
      #pragma unroll
      for (int t = 0; t < 2; t++) {
        f32x4 rsum = {};
        __builtin_amdgcn_s_setprio(1);
        #pragma unroll
        for (int kk = 0; kk < 2; kk++) {
          const bf16x8 pf = *(const bf16x8*)&Pl[wave*2 + t][l16][kk*32 + quad*8];
          #pragma unroll
          for (int nf = 0; nf < 4; nf++) {
            const bf16x8 vf = *(const bf16x8*)&Vs[(nf*16 + l16)*64 + ((kk*32 + quad*8) ^ xs)];
            acc[t][nf] = __builtin_amdgcn_mfma_f32_16x16x32_bf16(pf, vf, acc[t][nf], 0, 0, 0);
          }
          rsum = __builtin_amdgcn_mfma_f32_16x16x32_bf16(pf, ones, rsum, 0, 0, 0);
        }
        __builtin_amdgcn_s_setprio(0);
        #pragma unroll
        for (int r = 0; r < 4; r++) lrow[t][r] += rsum[r];
      }
    }
    __syncthreads();   // protect Ks/Vs before next staging
  }

  // ---- O /= l, write y (B,T,C) bf16 ----
  #pragma unroll
  for (int t = 0; t < 2; t++) {
    #pragma unroll
    for (int r = 0; r < 4; r++) {
      const float inv = 1.0f / lrow[t][r];
      const int trow = qs0 + t*16 + quad*4 + r;
      const size_t off = ((size_t)(b * SEQ + trow)) * D_MODEL + h * HDIM;
      #pragma unroll
      for (int nf = 0; nf < 4; nf++)
        Yb[off + nf*16 + l16] = f2bf(acc[t][nf][r] * inv);
    }
  }
}

extern "C" void kernel_launch(void* const* d_in, const int* in_sizes, int n_in,
                              void* d_out, int out_size, void* d_ws, size_t ws_size,
                              hipStream_t stream) {
  const float* x     = (const float*)d_in[0];
  const float* w_qkv = (const float*)d_in[1];
  const float* b_qkv = (const float*)d_in[2];
  const float* w_out = (const float*)d_in[3];
  const float* b_out = (const float*)d_in[4];
  float* out = (float*)d_out;

  const size_t SZ = (size_t)BATCH * NHEADS * SEQ * HDIM;   // 8M elems
  unsigned short* Qb  = (unsigned short*)d_ws;             // 16 MiB
  unsigned short* Kb  = Qb + SZ;                           // 16 MiB
  unsigned short* Vb  = Kb + SZ;                           // 16 MiB (V^T)
  unsigned short* Xb  = Vb + SZ;                           // 16 MiB, aliased by Yb
  unsigned short* Yb  = Xb;                                // attn writes after gemm0 reads
  unsigned short* WqT = Xb + SZ;                           // 6 MiB
  unsigned short* WoT = WqT + (size_t)3*D_MODEL*D_MODEL;   // 2 MiB

  cast_kernel<<<dim3((BATCH*SEQ*D_MODEL)/(256*8)), 256, 0, stream>>>(x, Xb);
  transpose_cast<<<dim3(3*D_MODEL/64, D_MODEL/64), 256, 0, stream>>>(w_qkv, WqT, 3*D_MODEL);
  transpose_cast<<<dim3(D_MODEL/64, D_MODEL/64), 256, 0, stream>>>(w_out, WoT, D_MODEL);

  gemm8p<0><<<dim3(3*D_MODEL/256, BATCH*SEQ/128), 512, 0, stream>>>(
      Xb, WqT, b_qkv, Qb, Kb, Vb, nullptr);
  attn_kernel<<<dim3(BATCH*NHEADS, 16), 256, 0, stream>>>(Qb, Kb, Vb, Yb);
  gemm8p<1><<<dim3(D_MODEL/256, BATCH*SEQ/128), 512, 0, stream>>>(
      Yb, WoT, b_out, nullptr, nullptr, nullptr, out);
}

// Round 3
// 253.106 us; speedup vs baseline: 1.0776x; 1.0776x over previous
//
#include <hip/hip_runtime.h>
#include <hip/hip_bf16.h>
#include <math.h>

#define D_MODEL 1024
#define NHEADS  16
#define HDIM    64
#define BATCH   4
#define SEQ     2048

typedef __attribute__((ext_vector_type(8))) short bf16x8;
typedef __attribute__((ext_vector_type(4))) float f32x4;

#if __has_builtin(__builtin_amdgcn_exp2f)
#define EXP2(x) __builtin_amdgcn_exp2f(x)
#else
#define EXP2(x) exp2f(x)
#endif

__device__ __forceinline__ unsigned short f2bf(float f) {
  union { float f; unsigned u; } v; v.f = f;
  unsigned r = v.u + 0x7FFFu + ((v.u >> 16) & 1u);   // RNE
  return (unsigned short)(r >> 16);
}

__device__ __forceinline__ void load_lds16(const unsigned short* g, unsigned short* l) {
  __builtin_amdgcn_global_load_lds(
      (const __attribute__((address_space(1))) unsigned int*)g,
      (__attribute__((address_space(3))) unsigned int*)l, 16, 0, 0);
}

// ---- pre-pass: fp32 -> bf16 cast (x) ----
__global__ __launch_bounds__(256) void cast_kernel(
    const float* __restrict__ in, unsigned short* __restrict__ out)
{
  const int idx = (blockIdx.x * 256 + threadIdx.x) * 8;
  float4 a = *(const float4*)&in[idx];
  float4 b = *(const float4*)&in[idx + 4];
  alignas(16) unsigned short t[8] = {
    f2bf(a.x), f2bf(a.y), f2bf(a.z), f2bf(a.w),
    f2bf(b.x), f2bf(b.y), f2bf(b.z), f2bf(b.w)};
  *(uint4*)&out[idx] = *(uint4*)t;
}

// ---- pre-pass: W [1024][N] fp32 -> WT [N][1024] bf16 ----
__global__ __launch_bounds__(256) void transpose_cast(
    const float* __restrict__ W, unsigned short* __restrict__ WT, int N)
{
  __shared__ float t[64][65];
  const int k0 = blockIdx.y * 64, n0 = blockIdx.x * 64;
  const int tid = threadIdx.x;
  const int r = tid >> 2, c0 = (tid & 3) * 16;
  #pragma unroll
  for (int i = 0; i < 16; i += 4) {
    float4 f = *(const float4*)&W[(size_t)(k0 + r) * N + n0 + c0 + i];
    t[r][c0+i] = f.x; t[r][c0+i+1] = f.y; t[r][c0+i+2] = f.z; t[r][c0+i+3] = f.w;
  }
  __syncthreads();
  #pragma unroll
  for (int i = 0; i < 16; i += 4) {
    alignas(8) unsigned short s[4] = {
      f2bf(t[c0+i][r]), f2bf(t[c0+i+1][r]), f2bf(t[c0+i+2][r]), f2bf(t[c0+i+3][r])};
    *(uint2*)&WT[(size_t)(n0 + r) * 1024 + k0 + c0 + i] = *(uint2*)s;
  }
}

#define BARRIER __builtin_amdgcn_s_barrier()
#define FENCE   asm volatile("" ::: "memory")
#define LGKM0   do { asm volatile("s_waitcnt lgkmcnt(0)" ::: "memory"); \
                     __builtin_amdgcn_sched_barrier(0); } while (0)

// ---- 128x256-tile fine-phased GEMM (unchanged) ----
template<int MODE>
__global__ __launch_bounds__(512, 2) void gemm8p(
    const unsigned short* __restrict__ A,
    const unsigned short* __restrict__ Bt,
    const float* __restrict__ bias,
    unsigned short* __restrict__ Qb, unsigned short* __restrict__ Kb,
    unsigned short* __restrict__ Vb, float* __restrict__ Out)
{
  constexpr int N  = (MODE == 0) ? 3 * D_MODEL : D_MODEL;
  constexpr int NT = D_MODEL / 64;                 // 16 K-tiles
  const int bn = blockIdx.x * 256;
  const int bm = blockIdx.y * 128;
  const int tid  = threadIdx.x;
  const int lane = tid & 63;
  const int w    = tid >> 6;
  const int quad = lane >> 4;
  const int l16  = lane & 15;
  const int wr = w >> 2, wc = w & 3;

  __shared__ __align__(16) unsigned short lds[49152];   // 96 KiB

  const int srow = lane >> 3;
  const int scol = ((lane & 7) ^ srow) * 8;
  const unsigned short* __restrict__ Ag = A  + (size_t)(bm + w*8 + srow) * D_MODEL + scol;
  const unsigned short* __restrict__ Bg = Bt + (size_t)(bn + w*8 + srow) * D_MODEL + scol;
  const int xs = (l16 & 7) * 8;

  f32x4 acc[4][4] = {};

  auto stageA = [&](int buf, int t2) {
    unsigned short* d = &lds[buf*8192 + w*512];
    const unsigned short* g = Ag + t2*64;
    load_lds16(g,                      d);
    load_lds16(g + (size_t)64*D_MODEL, d + 4096);
  };
  auto stageB = [&](int buf, int t2) {
    unsigned short* d = &lds[16384 + buf*16384 + w*512];
    const unsigned short* g = Bg + t2*64;
    #pragma unroll
    for (int c = 0; c < 4; c++)
      load_lds16(g + (size_t)c*64*D_MODEL, d + c*4096);
  };
  auto rdA = [&](int buf, int mi, int kk) {
    return *(const bf16x8*)&lds[buf*8192 +
        (wr*64 + mi*16 + l16)*64 + (((kk*4 + quad)*8) ^ xs)];
  };
  auto rdB = [&](int buf, int ni, int kk) {
    return *(const bf16x8*)&lds[16384 + buf*16384 +
        (wc*64 + ni*16 + l16)*64 + (((kk*4 + quad)*8) ^ xs)];
  };

  stageB(0, 0); stageA(0, 0);
  stageB(1, 1); stageA(1, 1);
  asm volatile("s_waitcnt vmcnt(6)" ::: "memory");
  BARRIER;
  FENCE;

  #pragma unroll 2
  for (int t = 0; t < NT; ++t) {
    const int cur  = t & 1;
    const bool pre = (t + 2 < NT);
    bf16x8 a0[2][2], a1[2][2], b0[2][2], b1[2][2];

    // phase 0
    #pragma unroll
    for (int kk = 0; kk < 2; kk++)
      #pragma unroll
      for (int i = 0; i < 2; i++) { a0[i][kk] = rdA(cur, i, kk); b0[i][kk] = rdB(cur, i, kk); }
    BARRIER; LGKM0;
    __builtin_amdgcn_s_setprio(1);
    #pragma unroll
    for (int kk = 0; kk < 2; kk++)
      #pragma unroll
      for (int mi = 0; mi < 2; mi++)
        #pragma unroll
        for (int ni = 0; ni < 2; ni++)
          acc[mi][ni] = __builtin_amdgcn_mfma_f32_16x16x32_bf16(a0[mi][kk], b0[ni][kk], acc[mi][ni], 0, 0, 0);
    __builtin_amdgcn_s_setprio(0);
    BARRIER;

    // phase 1
    #pragma unroll
    for (int kk = 0; kk < 2; kk++)
      #pragma unroll
      for (int i = 0; i < 2; i++) b1[i][kk] = rdB(cur, 2 + i, kk);
    BARRIER; LGKM0;
    __builtin_amdgcn_s_setprio(1);
    #pragma unroll
    for (int kk = 0; kk < 2; kk++)
      #pragma unroll
      for (int mi = 0; mi < 2; mi++)
        #pragma unroll
        for (int ni = 0; ni < 2; ni++)
          acc[mi][2+ni] = __builtin_amdgcn_mfma_f32_16x16x32_bf16(a0[mi][kk], b1[ni][kk], acc[mi][2+ni], 0, 0, 0);
    __builtin_amdgcn_s_setprio(0);
    BARRIER;

    // phase 2
    #pragma unroll
    for (int kk = 0; kk < 2; kk++)
      #pragma unroll
      for (int i = 0; i < 2; i++) a1[i][kk] = rdA(cur, 2 + i, kk);
    if (pre) stageB(cur, t + 2);
    BARRIER; LGKM0;
    __builtin_amdgcn_s_setprio(1);
    #pragma unroll
    for (int kk = 0; kk < 2; kk++)
      #pragma unroll
      for (int mi = 0; mi < 2; mi++)
        #pragma unroll
        for (int ni = 0; ni < 2; ni++)
          acc[2+mi][ni] = __builtin_amdgcn_mfma_f32_16x16x32_bf16(a1[mi][kk], b0[ni][kk], acc[2+mi][ni], 0, 0, 0);
    __builtin_amdgcn_s_setprio(0);
    BARRIER;

    // phase 3
    if (pre) {
      stageA(cur, t + 2);
      asm volatile("s_waitcnt vmcnt(6)" ::: "memory");
    } else {
      asm volatile("s_waitcnt vmcnt(0)" ::: "memory");
    }
    BARRIER;
    FENCE;
    __builtin_amdgcn_s_setprio(1);
    #pragma unroll
    for (int kk = 0; kk < 2; kk++)
      #pragma unroll
      for (int mi = 0; mi < 2; mi++)
        #pragma unroll
        for (int ni = 0; ni < 2; ni++)
          acc[2+mi][2+ni] = __builtin_amdgcn_mfma_f32_16x16x32_bf16(a1[mi][kk], b1[ni][kk], acc[2+mi][2+ni], 0, 0, 0);
    __builtin_amdgcn_s_setprio(0);
    BARRIER;
  }

  const int b   = bm >> 11;
  const int tl0 = (bm & (SEQ - 1));
  #pragma unroll
  for (int ni = 0; ni < 4; ni++) {
    const int n = bn + wc*64 + ni*16 + l16;
    const float bv = bias[n];
    #pragma unroll
    for (int mi = 0; mi < 4; mi++) {
      const int t0 = tl0 + wr*64 + mi*16 + quad*4;
      if (MODE == 0) {
        const int which = n >> 10;
        const int c = n & 1023;
        const int h = c >> 6, hd = c & 63;
        const size_t bhb = ((size_t)(b*NHEADS + h)) * (SEQ*HDIM);
        if (which == 2) {
          alignas(8) unsigned short pk[4];
          #pragma unroll
          for (int r = 0; r < 4; r++) pk[r] = f2bf(acc[mi][ni][r] + bv);
          *(uint2*)&Vb[bhb + (size_t)hd*SEQ + t0] = *(uint2*)pk;
        } else if (which == 0) {
          #pragma unroll
          for (int r = 0; r < 4; r++)
            Qb[bhb + (size_t)(t0 + r)*HDIM + hd] = f2bf((acc[mi][ni][r] + bv) * 0.18033688f);
        } else {
          #pragma unroll
          for (int r = 0; r < 4; r++)
            Kb[bhb + (size_t)(t0 + r)*HDIM + hd] = f2bf(acc[mi][ni][r] + bv);
        }
      } else {
        const int m = bm + wr*64 + mi*16 + quad*4;
        #pragma unroll
        for (int r = 0; r < 4; r++)
          Out[(size_t)(m + r) * N + n] = acc[mi][ni][r] + bv;
      }
    }
  }
}

// Flash attention v10: balanced (qt,15-qt) halves, K/V DOUBLE-BUFFER with
// stage-issued-before-compute (T3-min: drain at barrier waits on loads that
// had the whole compute phase to land), one barrier per tile, T2 swizzle,
// T5 setprio.
__global__ __launch_bounds__(256) void attn_kernel(
    const unsigned short* __restrict__ Qb,
    const unsigned short* __restrict__ Kb,
    const unsigned short* __restrict__ Vt,
    unsigned short* __restrict__ Yb)
{
  const int bh   = blockIdx.x;
  const int Gp   = blockIdx.y;                 // 0..7
  const int tid  = threadIdx.x;
  const int wave = tid >> 6;
  const int lane = tid & 63;
  const int quad = lane >> 4;
  const int l16  = lane & 15;

  __shared__ __align__(16) unsigned short Ks[2][64 * 64];   // [buf][key][hd], swz
  __shared__ __align__(16) unsigned short Vs[2][64 * 64];   // [buf][hd][key], swz
  __shared__ __align__(16) unsigned short Pl[8][16][72];    // per-strip P (bf16)

  const unsigned short* __restrict__ qb_ = Qb + (size_t)bh * (SEQ*HDIM);
  const unsigned short* __restrict__ kb_ = Kb + (size_t)bh * (SEQ*HDIM);
  const unsigned short* __restrict__ vb_ = Vt + (size_t)bh * (SEQ*HDIM);
  const int h = bh & (NHEADS - 1);
  const int b = bh >> 4;

  const short ob = (short)0x3F80;    // bf16 1.0
  const bf16x8 ones = {ob,ob,ob,ob,ob,ob,ob,ob};

  // staging geometry: LDS dest linear (wave slice + lane*16B); swizzle on the
  // per-lane GLOBAL source column (rule 21).
  const int srow = lane >> 3;                        // 0..7 within 8-row slice
  const int scolswz = ((lane & 7) ^ srow) * 8;       // swizzled 16B slot
  const int krow0 = wave * 16 + srow;                // key-row (K) / hd-row (V) base
  const int xs = (l16 & 7) * 8;                      // read-side XOR (elems)

  auto stage = [&](int buf, int it) {
    const int kb = it * 64;
    #pragma unroll
    for (int j = 0; j < 2; j++)
      load_lds16(kb_ + (size_t)(kb + krow0 + j*8)*HDIM + scolswz,
                 &Ks[buf][wave*1024 + j*512]);
    #pragma unroll
    for (int j = 0; j < 2; j++)
      load_lds16(vb_ + (size_t)(krow0 + j*8)*SEQ + kb + scolswz,
                 &Vs[buf][(wave*16 + j*8)*64]);
  };

  for (int half = 0; half < 2; half++) {
    const int qt = half ? (15 - Gp) : Gp;
    const int nt = 2 * qt + 2;
    const int qs0 = qt * 128 + wave * 32;
    const int myLast = 2 * qt + (wave >> 1);         // last tile this wave needs

    bf16x8 qf[2][2];
    #pragma unroll
    for (int t = 0; t < 2; t++)
      #pragma unroll
      for (int kk = 0; kk < 2; kk++)
        qf[t][kk] = *(const bf16x8*)(qb_ + (qs0 + t*16 + l16)*HDIM + kk*32 + quad*8);

    f32x4 acc[2][4] = {};
    float lrow[2][4] = {};

    // prologue: tile 0 into buf0 (syncthreads drains vmcnt)
    stage(0, 0);
    __syncthreads();

    for (int it = 0; it < nt; it++) {
      const int cur = it & 1;

      // ---- issue next tile's staging FIRST (hides latency under compute) ----
      if (it + 1 < nt) stage(cur ^ 1, it + 1);

      if (it <= myLast) {
        const int kb = it * 64;
        // ---- S for both strips (K-frag shared) ----
        f32x4 sfr[4] = {}, sfr1[4] = {};
        __builtin_amdgcn_s_setprio(1);
        #pragma unroll
        for (int kk = 0; kk < 2; kk++)
          #pragma unroll
          for (int nf = 0; nf < 4; nf++) {
            const bf16x8 kf = *(const bf16x8*)&Ks[cur][(nf*16 + l16)*64 + ((kk*32 + quad*8) ^ xs)];
            sfr[nf]  = __builtin_amdgcn_mfma_f32_16x16x32_bf16(qf[0][kk], kf, sfr[nf], 0, 0, 0);
            sfr1[nf] = __builtin_amdgcn_mfma_f32_16x16x32_bf16(qf[1][kk], kf, sfr1[nf], 0, 0, 0);
          }
        __builtin_amdgcn_s_setprio(0);

        // ---- causal mask on this wave's diagonal tile only ----
        if (it == myLast) {
          #pragma unroll
          for (int nf = 0; nf < 4; nf++) {
            const int kcol = kb + nf*16 + l16;
            #pragma unroll
            for (int r = 0; r < 4; r++) {
              sfr[nf][r]  = (kcol > qs0 + quad*4 + r)      ? -INFINITY : sfr[nf][r];
              sfr1[nf][r] = (kcol > qs0 + 16 + quad*4 + r) ? -INFINITY : sfr1[nf][r];
            }
          }
        }

        // ---- P = exp2(S) -> per-wave LDS bf16 (C-layout -> A-layout) ----
        #pragma unroll
        for (int nf = 0; nf < 4; nf++)
          #pragma unroll
          for (int r = 0; r < 4; r++) {
            Pl[wave*2 + 0][quad*4 + r][nf*16 + l16] = f2bf(EXP2(sfr[nf][r]));
            Pl[wave*2 + 1][quad*4 + r][nf*16 + l16] = f2bf(EXP2(sfr1[nf][r]));
          }

        // ---- PV for both strips (V-frags from LDS, swizzled) ----
        #pragma unroll
        for (int t = 0; t < 2; t++) {
          f32x4 rsum = {};
          __builtin_amdgcn_s_setprio(1);
          #pragma unroll
          for (int kk = 0; kk < 2; kk++) {
            const bf16x8 pf = *(const bf16x8*)&Pl[wave*2 + t][l16][kk*32 + quad*8];
            #pragma unroll
            for (int nf = 0; nf < 4; nf++) {
              const bf16x8 vf = *(const bf16x8*)&Vs[cur][(nf*16 + l16)*64 + ((kk*32 + quad*8) ^ xs)];
              acc[t][nf] = __builtin_amdgcn_mfma_f32_16x16x32_bf16(pf, vf, acc[t][nf], 0, 0, 0);
            }
            rsum = __builtin_amdgcn_mfma_f32_16x16x32_bf16(pf, ones, rsum, 0, 0, 0);
          }
          __builtin_amdgcn_s_setprio(0);
          #pragma unroll
          for (int r = 0; r < 4; r++) lrow[t][r] += rsum[r];
        }
      }

      // one barrier per tile: drains this wave's staging loads (issued at tile
      // top -> latency hidden) and protects buf[cur^1] reads next iteration.
      __syncthreads();
    }

    // ---- O /= l, write y (B,T,C) bf16 ----
    #pragma unroll
    for (int t = 0; t < 2; t++) {
      #pragma unroll
      for (int r = 0; r < 4; r++) {
        const float inv = 1.0f / lrow[t][r];
        const int trow = qs0 + t*16 + quad*4 + r;
        const size_t off = ((size_t)(b * SEQ + trow)) * D_MODEL + h * HDIM;
        #pragma unroll
        for (int nf = 0; nf < 4; nf++)
          Yb[off + nf*16 + l16] = f2bf(acc[t][nf][r] * inv);
      }
    }
  }
}

extern "C" void kernel_launch(void* const* d_in, const int* in_sizes, int n_in,
                              void* d_out, int out_size, void* d_ws, size_t ws_size,
                              hipStream_t stream) {
  const float* x     = (const float*)d_in[0];
  const float* w_qkv = (const float*)d_in[1];
  const float* b_qkv = (const float*)d_in[2];
  const float* w_out = (const float*)d_in[3];
  const float* b_out = (const float*)d_in[4];
  float* out = (float*)d_out;

  const size_t SZ = (size_t)BATCH * NHEADS * SEQ * HDIM;   // 8M elems
  unsigned short* Qb  = (unsigned short*)d_ws;             // 16 MiB
  unsigned short* Kb  = Qb + SZ;                           // 16 MiB
  unsigned short* Vb  = Kb + SZ;                           // 16 MiB (V^T)
  unsigned short* Xb  = Vb + SZ;                           // 16 MiB, aliased by Yb
  unsigned short* Yb  = Xb;                                // attn writes after gemm0 reads
  unsigned short* WqT = Xb + SZ;                           // 6 MiB
  unsigned short* WoT = WqT + (size_t)3*D_MODEL*D_MODEL;   // 2 MiB

  cast_kernel<<<dim3((BATCH*SEQ*D_MODEL)/(256*8)), 256, 0, stream>>>(x, Xb);
  transpose_cast<<<dim3(3*D_MODEL/64, D_MODEL/64), 256, 0, stream>>>(w_qkv, WqT, 3*D_MODEL);
  transpose_cast<<<dim3(D_MODEL/64, D_MODEL/64), 256, 0, stream>>>(w_out, WoT, D_MODEL);

  gemm8p<0><<<dim3(3*D_MODEL/256, BATCH*SEQ/128), 512, 0, stream>>>(
      Xb, WqT, b_qkv, Qb, Kb, Vb, nullptr);
  attn_kernel<<<dim3(BATCH*NHEADS, 8), 256, 0, stream>>>(Qb, Kb, Vb, Yb);
  gemm8p<1><<<dim3(D_MODEL/256, BATCH*SEQ/128), 512, 0, stream>>>(
      Yb, WoT, b_out, nullptr, nullptr, nullptr, out);
}

// Round 4
// 252.222 us; speedup vs baseline: 1.0814x; 1.0035x over previous
//
#include <hip/hip_runtime.h>
#include <hip/hip_bf16.h>
#include <math.h>

#define D_MODEL 1024
#define NHEADS  16
#define HDIM    64
#define BATCH   4
#define SEQ     2048

typedef __attribute__((ext_vector_type(8))) short bf16x8;
typedef __attribute__((ext_vector_type(4))) float f32x4;

#if __has_builtin(__builtin_amdgcn_exp2f)
#define EXP2(x) __builtin_amdgcn_exp2f(x)
#else
#define EXP2(x) exp2f(x)
#endif

__device__ __forceinline__ unsigned short f2bf(float f) {
  union { float f; unsigned u; } v; v.f = f;
  unsigned r = v.u + 0x7FFFu + ((v.u >> 16) & 1u);   // RNE
  return (unsigned short)(r >> 16);
}

// pack 2 f32 -> 2 bf16 in one dword (RNE), hw instruction (no builtin, m240)
__device__ __forceinline__ unsigned cvtpk(float lo, float hi) {
  unsigned r;
  asm("v_cvt_pk_bf16_f32 %0, %1, %2" : "=v"(r) : "v"(lo), "v"(hi));
  return r;
}

__device__ __forceinline__ void load_lds16(const unsigned short* g, unsigned short* l) {
  __builtin_amdgcn_global_load_lds(
      (const __attribute__((address_space(1))) unsigned int*)g,
      (__attribute__((address_space(3))) unsigned int*)l, 16, 0, 0);
}

// ---- pre-pass: fp32 -> bf16 cast (x) ----
__global__ __launch_bounds__(256) void cast_kernel(
    const float* __restrict__ in, unsigned short* __restrict__ out)
{
  const int idx = (blockIdx.x * 256 + threadIdx.x) * 8;
  float4 a = *(const float4*)&in[idx];
  float4 b = *(const float4*)&in[idx + 4];
  alignas(16) unsigned short t[8] = {
    f2bf(a.x), f2bf(a.y), f2bf(a.z), f2bf(a.w),
    f2bf(b.x), f2bf(b.y), f2bf(b.z), f2bf(b.w)};
  *(uint4*)&out[idx] = *(uint4*)t;
}

// ---- pre-pass: W [1024][N] fp32 -> WT [N][1024] bf16 ----
__global__ __launch_bounds__(256) void transpose_cast(
    const float* __restrict__ W, unsigned short* __restrict__ WT, int N)
{
  __shared__ float t[64][65];
  const int k0 = blockIdx.y * 64, n0 = blockIdx.x * 64;
  const int tid = threadIdx.x;
  const int r = tid >> 2, c0 = (tid & 3) * 16;
  #pragma unroll
  for (int i = 0; i < 16; i += 4) {
    float4 f = *(const float4*)&W[(size_t)(k0 + r) * N + n0 + c0 + i];
    t[r][c0+i] = f.x; t[r][c0+i+1] = f.y; t[r][c0+i+2] = f.z; t[r][c0+i+3] = f.w;
  }
  __syncthreads();
  #pragma unroll
  for (int i = 0; i < 16; i += 4) {
    alignas(8) unsigned short s[4] = {
      f2bf(t[c0+i][r]), f2bf(t[c0+i+1][r]), f2bf(t[c0+i+2][r]), f2bf(t[c0+i+3][r])};
    *(uint2*)&WT[(size_t)(n0 + r) * 1024 + k0 + c0 + i] = *(uint2*)s;
  }
}

#define BARRIER __builtin_amdgcn_s_barrier()
#define FENCE   asm volatile("" ::: "memory")
#define LGKM0   do { asm volatile("s_waitcnt lgkmcnt(0)" ::: "memory"); \
                     __builtin_amdgcn_sched_barrier(0); } while (0)

// ---- 128x256-tile fine-phased GEMM (unchanged) ----
template<int MODE>
__global__ __launch_bounds__(512, 2) void gemm8p(
    const unsigned short* __restrict__ A,
    const unsigned short* __restrict__ Bt,
    const float* __restrict__ bias,
    unsigned short* __restrict__ Qb, unsigned short* __restrict__ Kb,
    unsigned short* __restrict__ Vb, float* __restrict__ Out)
{
  constexpr int N  = (MODE == 0) ? 3 * D_MODEL : D_MODEL;
  constexpr int NT = D_MODEL / 64;                 // 16 K-tiles
  const int bn = blockIdx.x * 256;
  const int bm = blockIdx.y * 128;
  const int tid  = threadIdx.x;
  const int lane = tid & 63;
  const int w    = tid >> 6;
  const int quad = lane >> 4;
  const int l16  = lane & 15;
  const int wr = w >> 2, wc = w & 3;

  __shared__ __align__(16) unsigned short lds[49152];   // 96 KiB

  const int srow = lane >> 3;
  const int scol = ((lane & 7) ^ srow) * 8;
  const unsigned short* __restrict__ Ag = A  + (size_t)(bm + w*8 + srow) * D_MODEL + scol;
  const unsigned short* __restrict__ Bg = Bt + (size_t)(bn + w*8 + srow) * D_MODEL + scol;
  const int xs = (l16 & 7) * 8;

  f32x4 acc[4][4] = {};

  auto stageA = [&](int buf, int t2) {
    unsigned short* d = &lds[buf*8192 + w*512];
    const unsigned short* g = Ag + t2*64;
    load_lds16(g,                      d);
    load_lds16(g + (size_t)64*D_MODEL, d + 4096);
  };
  auto stageB = [&](int buf, int t2) {
    unsigned short* d = &lds[16384 + buf*16384 + w*512];
    const unsigned short* g = Bg + t2*64;
    #pragma unroll
    for (int c = 0; c < 4; c++)
      load_lds16(g + (size_t)c*64*D_MODEL, d + c*4096);
  };
  auto rdA = [&](int buf, int mi, int kk) {
    return *(const bf16x8*)&lds[buf*8192 +
        (wr*64 + mi*16 + l16)*64 + (((kk*4 + quad)*8) ^ xs)];
  };
  auto rdB = [&](int buf, int ni, int kk) {
    return *(const bf16x8*)&lds[16384 + buf*16384 +
        (wc*64 + ni*16 + l16)*64 + (((kk*4 + quad)*8) ^ xs)];
  };

  stageB(0, 0); stageA(0, 0);
  stageB(1, 1); stageA(1, 1);
  asm volatile("s_waitcnt vmcnt(6)" ::: "memory");
  BARRIER;
  FENCE;

  #pragma unroll 2
  for (int t = 0; t < NT; ++t) {
    const int cur  = t & 1;
    const bool pre = (t + 2 < NT);
    bf16x8 a0[2][2], a1[2][2], b0[2][2], b1[2][2];

    // phase 0
    #pragma unroll
    for (int kk = 0; kk < 2; kk++)
      #pragma unroll
      for (int i = 0; i < 2; i++) { a0[i][kk] = rdA(cur, i, kk); b0[i][kk] = rdB(cur, i, kk); }
    BARRIER; LGKM0;
    __builtin_amdgcn_s_setprio(1);
    #pragma unroll
    for (int kk = 0; kk < 2; kk++)
      #pragma unroll
      for (int mi = 0; mi < 2; mi++)
        #pragma unroll
        for (int ni = 0; ni < 2; ni++)
          acc[mi][ni] = __builtin_amdgcn_mfma_f32_16x16x32_bf16(a0[mi][kk], b0[ni][kk], acc[mi][ni], 0, 0, 0);
    __builtin_amdgcn_s_setprio(0);
    BARRIER;

    // phase 1
    #pragma unroll
    for (int kk = 0; kk < 2; kk++)
      #pragma unroll
      for (int i = 0; i < 2; i++) b1[i][kk] = rdB(cur, 2 + i, kk);
    BARRIER; LGKM0;
    __builtin_amdgcn_s_setprio(1);
    #pragma unroll
    for (int kk = 0; kk < 2; kk++)
      #pragma unroll
      for (int mi = 0; mi < 2; mi++)
        #pragma unroll
        for (int ni = 0; ni < 2; ni++)
          acc[mi][2+ni] = __builtin_amdgcn_mfma_f32_16x16x32_bf16(a0[mi][kk], b1[ni][kk], acc[mi][2+ni], 0, 0, 0);
    __builtin_amdgcn_s_setprio(0);
    BARRIER;

    // phase 2
    #pragma unroll
    for (int kk = 0; kk < 2; kk++)
      #pragma unroll
      for (int i = 0; i < 2; i++) a1[i][kk] = rdA(cur, 2 + i, kk);
    if (pre) stageB(cur, t + 2);
    BARRIER; LGKM0;
    __builtin_amdgcn_s_setprio(1);
    #pragma unroll
    for (int kk = 0; kk < 2; kk++)
      #pragma unroll
      for (int mi = 0; mi < 2; mi++)
        #pragma unroll
        for (int ni = 0; ni < 2; ni++)
          acc[2+mi][ni] = __builtin_amdgcn_mfma_f32_16x16x32_bf16(a1[mi][kk], b0[ni][kk], acc[2+mi][ni], 0, 0, 0);
    __builtin_amdgcn_s_setprio(0);
    BARRIER;

    // phase 3
    if (pre) {
      stageA(cur, t + 2);
      asm volatile("s_waitcnt vmcnt(6)" ::: "memory");
    } else {
      asm volatile("s_waitcnt vmcnt(0)" ::: "memory");
    }
    BARRIER;
    FENCE;
    __builtin_amdgcn_s_setprio(1);
    #pragma unroll
    for (int kk = 0; kk < 2; kk++)
      #pragma unroll
      for (int mi = 0; mi < 2; mi++)
        #pragma unroll
        for (int ni = 0; ni < 2; ni++)
          acc[2+mi][2+ni] = __builtin_amdgcn_mfma_f32_16x16x32_bf16(a1[mi][kk], b1[ni][kk], acc[2+mi][2+ni], 0, 0, 0);
    __builtin_amdgcn_s_setprio(0);
    BARRIER;
  }

  const int b   = bm >> 11;
  const int tl0 = (bm & (SEQ - 1));
  #pragma unroll
  for (int ni = 0; ni < 4; ni++) {
    const int n = bn + wc*64 + ni*16 + l16;
    const float bv = bias[n];
    #pragma unroll
    for (int mi = 0; mi < 4; mi++) {
      const int t0 = tl0 + wr*64 + mi*16 + quad*4;
      if (MODE == 0) {
        const int which = n >> 10;
        const int c = n & 1023;
        const int h = c >> 6, hd = c & 63;
        const size_t bhb = ((size_t)(b*NHEADS + h)) * (SEQ*HDIM);
        if (which == 2) {
          alignas(8) unsigned short pk[4];
          #pragma unroll
          for (int r = 0; r < 4; r++) pk[r] = f2bf(acc[mi][ni][r] + bv);
          *(uint2*)&Vb[bhb + (size_t)hd*SEQ + t0] = *(uint2*)pk;
        } else if (which == 0) {
          #pragma unroll
          for (int r = 0; r < 4; r++)
            Qb[bhb + (size_t)(t0 + r)*HDIM + hd] = f2bf((acc[mi][ni][r] + bv) * 0.18033688f);
        } else {
          #pragma unroll
          for (int r = 0; r < 4; r++)
            Kb[bhb + (size_t)(t0 + r)*HDIM + hd] = f2bf(acc[mi][ni][r] + bv);
        }
      } else {
        const int m = bm + wr*64 + mi*16 + quad*4;
        #pragma unroll
        for (int r = 0; r < 4; r++)
          Out[(size_t)(m + r) * N + n] = acc[mi][ni][r] + bv;
      }
    }
  }
}

// Flash attention v11: v10 structure (balanced halves, K/V double-buffer,
// stage-early, one barrier/tile, T2 swizzle, T5 setprio) + T12-lite softmax:
// SWAPPED QK^T (mfma(K,Q) -> lane = q-row, regs span 4 consecutive k-cols),
// v_cvt_pk_bf16_f32 packing, ds_write_b64 P-writes.
__global__ __launch_bounds__(256) void attn_kernel(
    const unsigned short* __restrict__ Qb,
    const unsigned short* __restrict__ Kb,
    const unsigned short* __restrict__ Vt,
    unsigned short* __restrict__ Yb)
{
  const int bh   = blockIdx.x;
  const int Gp   = blockIdx.y;                 // 0..7
  const int tid  = threadIdx.x;
  const int wave = tid >> 6;
  const int lane = tid & 63;
  const int quad = lane >> 4;
  const int l16  = lane & 15;

  __shared__ __align__(16) unsigned short Ks[2][64 * 64];   // [buf][key][hd], swz
  __shared__ __align__(16) unsigned short Vs[2][64 * 64];   // [buf][hd][key], swz
  __shared__ __align__(16) unsigned short Pl[8][16][72];    // per-strip P (bf16)

  const unsigned short* __restrict__ qb_ = Qb + (size_t)bh * (SEQ*HDIM);
  const unsigned short* __restrict__ kb_ = Kb + (size_t)bh * (SEQ*HDIM);
  const unsigned short* __restrict__ vb_ = Vt + (size_t)bh * (SEQ*HDIM);
  const int h = bh & (NHEADS - 1);
  const int b = bh >> 4;

  const short ob = (short)0x3F80;    // bf16 1.0
  const bf16x8 ones = {ob,ob,ob,ob,ob,ob,ob,ob};

  // staging geometry: LDS dest linear (wave slice + lane*16B); swizzle on the
  // per-lane GLOBAL source column (rule 21).
  const int srow = lane >> 3;                        // 0..7 within 8-row slice
  const int scolswz = ((lane & 7) ^ srow) * 8;       // swizzled 16B slot
  const int krow0 = wave * 16 + srow;                // key-row (K) / hd-row (V) base
  const int xs = (l16 & 7) * 8;                      // read-side XOR (elems)

  auto stage = [&](int buf, int it) {
    const int kb = it * 64;
    #pragma unroll
    for (int j = 0; j < 2; j++)
      load_lds16(kb_ + (size_t)(kb + krow0 + j*8)*HDIM + scolswz,
                 &Ks[buf][wave*1024 + j*512]);
    #pragma unroll
    for (int j = 0; j < 2; j++)
      load_lds16(vb_ + (size_t)(krow0 + j*8)*SEQ + kb + scolswz,
                 &Vs[buf][(wave*16 + j*8)*64]);
  };

  for (int half = 0; half < 2; half++) {
    const int qt = half ? (15 - Gp) : Gp;
    const int nt = 2 * qt + 2;
    const int qs0 = qt * 128 + wave * 32;
    const int myLast = 2 * qt + (wave >> 1);         // last tile this wave needs

    bf16x8 qf[2][2];
    #pragma unroll
    for (int t = 0; t < 2; t++)
      #pragma unroll
      for (int kk = 0; kk < 2; kk++)
        qf[t][kk] = *(const bf16x8*)(qb_ + (qs0 + t*16 + l16)*HDIM + kk*32 + quad*8);

    f32x4 acc[2][4] = {};
    float lrow[2][4] = {};

    // prologue: tile 0 into buf0 (syncthreads drains vmcnt)
    stage(0, 0);
    __syncthreads();

    for (int it = 0; it < nt; it++) {
      const int cur = it & 1;

      // ---- issue next tile's staging FIRST (hides latency under compute) ----
      if (it + 1 < nt) stage(cur ^ 1, it + 1);

      if (it <= myLast) {
        const int kb = it * 64;
        // ---- S^T for both strips: swapped operands ->
        //      sfr[nf][r] = S[key = kb+nf*16+quad*4+r][q = qs0+strip*16+l16] ----
        f32x4 sfr[4] = {}, sfr1[4] = {};
        __builtin_amdgcn_s_setprio(1);
        #pragma unroll
        for (int kk = 0; kk < 2; kk++)
          #pragma unroll
          for (int nf = 0; nf < 4; nf++) {
            const bf16x8 kf = *(const bf16x8*)&Ks[cur][(nf*16 + l16)*64 + ((kk*32 + quad*8) ^ xs)];
            sfr[nf]  = __builtin_amdgcn_mfma_f32_16x16x32_bf16(kf, qf[0][kk], sfr[nf], 0, 0, 0);
            sfr1[nf] = __builtin_amdgcn_mfma_f32_16x16x32_bf16(kf, qf[1][kk], sfr1[nf], 0, 0, 0);
          }
        __builtin_amdgcn_s_setprio(0);

        // ---- causal mask on this wave's diagonal tile only ----
        if (it == myLast) {
          #pragma unroll
          for (int nf = 0; nf < 4; nf++) {
            const int key = kb + nf*16 + quad*4;
            #pragma unroll
            for (int r = 0; r < 4; r++) {
              sfr[nf][r]  = (key + r > qs0 + l16)      ? -INFINITY : sfr[nf][r];
              sfr1[nf][r] = (key + r > qs0 + 16 + l16) ? -INFINITY : sfr1[nf][r];
            }
          }
        }

        // ---- P = exp2(S), pack pairs (hw cvt_pk), b64 write:
        //      Pl[strip][qrow = l16][kcol = nf*16 + quad*4 .. +3] ----
        #pragma unroll
        for (int nf = 0; nf < 4; nf++) {
          uint2 p0, p1;
          p0.x = cvtpk(EXP2(sfr[nf][0]),  EXP2(sfr[nf][1]));
          p0.y = cvtpk(EXP2(sfr[nf][2]),  EXP2(sfr[nf][3]));
          p1.x = cvtpk(EXP2(sfr1[nf][0]), EXP2(sfr1[nf][1]));
          p1.y = cvtpk(EXP2(sfr1[nf][2]), EXP2(sfr1[nf][3]));
          *(uint2*)&Pl[wave*2 + 0][l16][nf*16 + quad*4] = p0;
          *(uint2*)&Pl[wave*2 + 1][l16][nf*16 + quad*4] = p1;
        }

        // ---- PV for both strips (V-frags from LDS, swizzled) ----
        #pragma unroll
        for (int t = 0; t < 2; t++) {
          f32x4 rsum = {};
          __builtin_amdgcn_s_setprio(1);
          #pragma unroll
          for (int kk = 0; kk < 2; kk++) {
            const bf16x8 pf = *(const bf16x8*)&Pl[wave*2 + t][l16][kk*32 + quad*8];
            #pragma unroll
            for (int nf = 0; nf < 4; nf++) {
              const bf16x8 vf = *(const bf16x8*)&Vs[cur][(nf*16 + l16)*64 + ((kk*32 + quad*8) ^ xs)];
              acc[t][nf] = __builtin_amdgcn_mfma_f32_16x16x32_bf16(pf, vf, acc[t][nf], 0, 0, 0);
            }
            rsum = __builtin_amdgcn_mfma_f32_16x16x32_bf16(pf, ones, rsum, 0, 0, 0);
          }
          __builtin_amdgcn_s_setprio(0);
          #pragma unroll
          for (int r = 0; r < 4; r++) lrow[t][r] += rsum[r];
        }
      }

      // one barrier per tile: drains this wave's staging loads (issued at tile
      // top -> latency hidden) and protects buf[cur^1] reads next iteration.
      __syncthreads();
    }

    // ---- O /= l, write y (B,T,C) bf16 ----
    #pragma unroll
    for (int t = 0; t < 2; t++) {
      #pragma unroll
      for (int r = 0; r < 4; r++) {
        const float inv = 1.0f / lrow[t][r];
        const int trow = qs0 + t*16 + quad*4 + r;
        const size_t off = ((size_t)(b * SEQ + trow)) * D_MODEL + h * HDIM;
        #pragma unroll
        for (int nf = 0; nf < 4; nf++)
          Yb[off + nf*16 + l16] = f2bf(acc[t][nf][r] * inv);
      }
    }
  }
}

extern "C" void kernel_launch(void* const* d_in, const int* in_sizes, int n_in,
                              void* d_out, int out_size, void* d_ws, size_t ws_size,
                              hipStream_t stream) {
  const float* x     = (const float*)d_in[0];
  const float* w_qkv = (const float*)d_in[1];
  const float* b_qkv = (const float*)d_in[2];
  const float* w_out = (const float*)d_in[3];
  const float* b_out = (const float*)d_in[4];
  float* out = (float*)d_out;

  const size_t SZ = (size_t)BATCH * NHEADS * SEQ * HDIM;   // 8M elems
  unsigned short* Qb  = (unsigned short*)d_ws;             // 16 MiB
  unsigned short* Kb  = Qb + SZ;                           // 16 MiB
  unsigned short* Vb  = Kb + SZ;                           // 16 MiB (V^T)
  unsigned short* Xb  = Vb + SZ;                           // 16 MiB, aliased by Yb
  unsigned short* Yb  = Xb;                                // attn writes after gemm0 reads
  unsigned short* WqT = Xb + SZ;                           // 6 MiB
  unsigned short* WoT = WqT + (size_t)3*D_MODEL*D_MODEL;   // 2 MiB

  cast_kernel<<<dim3((BATCH*SEQ*D_MODEL)/(256*8)), 256, 0, stream>>>(x, Xb);
  transpose_cast<<<dim3(3*D_MODEL/64, D_MODEL/64), 256, 0, stream>>>(w_qkv, WqT, 3*D_MODEL);
  transpose_cast<<<dim3(D_MODEL/64, D_MODEL/64), 256, 0, stream>>>(w_out, WoT, D_MODEL);

  gemm8p<0><<<dim3(3*D_MODEL/256, BATCH*SEQ/128), 512, 0, stream>>>(
      Xb, WqT, b_qkv, Qb, Kb, Vb, nullptr);
  attn_kernel<<<dim3(BATCH*NHEADS, 8), 256, 0, stream>>>(Qb, Kb, Vb, Yb);
  gemm8p<1><<<dim3(D_MODEL/256, BATCH*SEQ/128), 512, 0, stream>>>(
      Yb, WoT, b_out, nullptr, nullptr, nullptr, out);
}

// Round 5
// 245.408 us; speedup vs baseline: 1.1114x; 1.0278x over previous
//
#include <hip/hip_runtime.h>
#include <hip/hip_bf16.h>
#include <math.h>

#define D_MODEL 1024
#define NHEADS  16
#define HDIM    64
#define BATCH   4
#define SEQ     2048

typedef __attribute__((ext_vector_type(8))) short bf16x8;
typedef __attribute__((ext_vector_type(4))) float f32x4;

#if __has_builtin(__builtin_amdgcn_exp2f)
#define EXP2(x) __builtin_amdgcn_exp2f(x)
#else
#define EXP2(x) exp2f(x)
#endif

__device__ __forceinline__ unsigned short f2bf(float f) {
  union { float f; unsigned u; } v; v.f = f;
  unsigned r = v.u + 0x7FFFu + ((v.u >> 16) & 1u);   // RNE
  return (unsigned short)(r >> 16);
}

// pack 2 f32 -> 2 bf16 in one dword (RNE), hw instruction (no builtin, m240)
__device__ __forceinline__ unsigned cvtpk(float lo, float hi) {
  unsigned r;
  asm("v_cvt_pk_bf16_f32 %0, %1, %2" : "=v"(r) : "v"(lo), "v"(hi));
  return r;
}

__device__ __forceinline__ void load_lds16(const unsigned short* g, unsigned short* l) {
  __builtin_amdgcn_global_load_lds(
      (const __attribute__((address_space(1))) unsigned int*)g,
      (__attribute__((address_space(3))) unsigned int*)l, 16, 0, 0);
}

// ---- fused pre-pass: x cast (blocks 0..4095), w_qkv transpose (4096..4863),
//      w_out transpose (4864..5119). One launch instead of three. ----
__global__ __launch_bounds__(256) void prep_kernel(
    const float* __restrict__ x,     unsigned short* __restrict__ Xb,
    const float* __restrict__ w_qkv, unsigned short* __restrict__ WqT,
    const float* __restrict__ w_out, unsigned short* __restrict__ WoT)
{
  __shared__ float t[64][65];
  const int id  = blockIdx.x;
  const int tid = threadIdx.x;

  if (id < 4096) {                       // ---- cast chunk ----
    const int idx = (id * 256 + tid) * 8;
    float4 a = *(const float4*)&x[idx];
    float4 b = *(const float4*)&x[idx + 4];
    alignas(16) unsigned short o[8] = {
      f2bf(a.x), f2bf(a.y), f2bf(a.z), f2bf(a.w),
      f2bf(b.x), f2bf(b.y), f2bf(b.z), f2bf(b.w)};
    *(uint4*)&Xb[idx] = *(uint4*)o;
    return;
  }

  // ---- transpose_cast: W [1024][N] fp32 -> WT [N][1024] bf16 ----
  const float* W; unsigned short* WT; int N, rblk;
  if (id < 4096 + 768) { W = w_qkv; WT = WqT; N = 3 * D_MODEL; rblk = id - 4096; }
  else                 { W = w_out; WT = WoT; N = D_MODEL;     rblk = id - 4864; }
  const int gx = N / 64;
  const int n0 = (rblk % gx) * 64, k0 = (rblk / gx) * 64;
  const int r = tid >> 2, c0 = (tid & 3) * 16;
  #pragma unroll
  for (int i = 0; i < 16; i += 4) {
    float4 f = *(const float4*)&W[(size_t)(k0 + r) * N + n0 + c0 + i];
    t[r][c0+i] = f.x; t[r][c0+i+1] = f.y; t[r][c0+i+2] = f.z; t[r][c0+i+3] = f.w;
  }
  __syncthreads();
  #pragma unroll
  for (int i = 0; i < 16; i += 4) {
    alignas(8) unsigned short s[4] = {
      f2bf(t[c0+i][r]), f2bf(t[c0+i+1][r]), f2bf(t[c0+i+2][r]), f2bf(t[c0+i+3][r])};
    *(uint2*)&WT[(size_t)(n0 + r) * 1024 + k0 + c0 + i] = *(uint2*)s;
  }
}

// ---- 128x256-tile double-buffered GEMM: C[M x N] = A @ BT^T + bias.
// 8 waves, per-wave 64x64 output. Classic 2-buffer: stage(t+1) issued at tile
// top, ONE barrier per K-tile (its vmcnt drain waits on loads issued a full
// tile earlier -> latency hidden; no in-place restage hazard). T2 swizzle
// (conflicts measured 0), T5 setprio, T1 bijective XCD swizzle.
template<int MODE>
__global__ __launch_bounds__(512, 2) void gemm_db(
    const unsigned short* __restrict__ A,
    const unsigned short* __restrict__ Bt,
    const float* __restrict__ bias,
    unsigned short* __restrict__ Qb, unsigned short* __restrict__ Kb,
    unsigned short* __restrict__ Vb, float* __restrict__ Out)
{
  constexpr int N   = (MODE == 0) ? 3 * D_MODEL : D_MODEL;
  constexpr int NT  = D_MODEL / 64;                // 16 K-tiles
  constexpr int GX  = N / 256;                     // 12 or 4
  constexpr int NWG = GX * (BATCH * SEQ / 128);    // 768 or 256 (both %8==0)

  // T1: bijective XCD swizzle (block i -> XCD i%8); each XCD gets a
  // contiguous chunk of NWG/8 ids = 8 full M-rows -> panel reuse in its L2.
  int id = blockIdx.y * GX + blockIdx.x;
  id = (id & 7) * (NWG >> 3) + (id >> 3);
  const int bn = (id % GX) * 256;
  const int bm = (id / GX) * 128;

  const int tid  = threadIdx.x;
  const int lane = tid & 63;
  const int w    = tid >> 6;
  const int quad = lane >> 4;
  const int l16  = lane & 15;
  const int wr = w >> 2, wc = w & 3;

  // A: [2][128][64] @ 0 (8192 shorts/buf), B: [2][256][64] @ 16384
  __shared__ __align__(16) unsigned short lds[49152];   // 96 KiB

  // staging: linear LDS dest, swizzle on per-lane GLOBAL source (rule 21)
  const int srow = lane >> 3;
  const int scol = ((lane & 7) ^ srow) * 8;
  const unsigned short* __restrict__ Ag = A  + (size_t)(bm + w*8 + srow) * D_MODEL + scol;
  const unsigned short* __restrict__ Bg = Bt + (size_t)(bn + w*8 + srow) * D_MODEL + scol;
  const int xs = (l16 & 7) * 8;                    // read-side XOR (elems)

  f32x4 acc[4][4] = {};

  auto stageAll = [&](int buf, int t2) {           // 6 loads/wave
    unsigned short* dA = &lds[buf*8192 + w*512];
    unsigned short* dB = &lds[16384 + buf*16384 + w*512];
    const unsigned short* gA = Ag + t2*64;
    const unsigned short* gB = Bg + t2*64;
    load_lds16(gA,                      dA);
    load_lds16(gA + (size_t)64*D_MODEL, dA + 4096);
    #pragma unroll
    for (int c = 0; c < 4; c++)
      load_lds16(gB + (size_t)c*64*D_MODEL, dB + c*4096);
  };
  auto rdA = [&](int buf, int mi, int kk) {
    return *(const bf16x8*)&lds[buf*8192 +
        (wr*64 + mi*16 + l16)*64 + (((kk*4 + quad)*8) ^ xs)];
  };
  auto rdB = [&](int buf, int ni, int kk) {
    return *(const bf16x8*)&lds[16384 + buf*16384 +
        (wc*64 + ni*16 + l16)*64 + (((kk*4 + quad)*8) ^ xs)];
  };

  stageAll(0, 0);
  __syncthreads();                                  // drain: tile 0 ready

  for (int t = 0; t < NT; ++t) {
    const int cur = t & 1;
    if (t + 1 < NT) stageAll(cur ^ 1, t + 1);       // issue-early: hides under compute

    #pragma unroll
    for (int kk = 0; kk < 2; kk++) {
      bf16x8 af[4], bfv[4];
      #pragma unroll
      for (int mi = 0; mi < 4; mi++) af[mi]  = rdA(cur, mi, kk);
      #pragma unroll
      for (int ni = 0; ni < 4; ni++) bfv[ni] = rdB(cur, ni, kk);
      __builtin_amdgcn_s_setprio(1);
      #pragma unroll
      for (int mi = 0; mi < 4; mi++)
        #pragma unroll
        for (int ni = 0; ni < 4; ni++)
          acc[mi][ni] = __builtin_amdgcn_mfma_f32_16x16x32_bf16(af[mi], bfv[ni], acc[mi][ni], 0, 0, 0);
      __builtin_amdgcn_s_setprio(0);
    }

    // one barrier per K-tile: per-wave vmcnt/lgkm drain (loads had a full
    // tile of compute to land) + protects buf[cur^1] for next iteration.
    __syncthreads();
  }

  // ---- epilogue (per-wave tile = 64x64) ----
  const int b   = bm >> 11;
  const int tl0 = (bm & (SEQ - 1));
  #pragma unroll
  for (int ni = 0; ni < 4; ni++) {
    const int n = bn + wc*64 + ni*16 + l16;
    const float bv = bias[n];
    #pragma unroll
    for (int mi = 0; mi < 4; mi++) {
      const int t0 = tl0 + wr*64 + mi*16 + quad*4;
      if (MODE == 0) {
        const int which = n >> 10;
        const int c = n & 1023;
        const int h = c >> 6, hd = c & 63;
        const size_t bhb = ((size_t)(b*NHEADS + h)) * (SEQ*HDIM);
        if (which == 2) {
          alignas(8) unsigned short pk[4];
          #pragma unroll
          for (int r = 0; r < 4; r++) pk[r] = f2bf(acc[mi][ni][r] + bv);
          *(uint2*)&Vb[bhb + (size_t)hd*SEQ + t0] = *(uint2*)pk;
        } else if (which == 0) {
          #pragma unroll
          for (int r = 0; r < 4; r++)
            Qb[bhb + (size_t)(t0 + r)*HDIM + hd] = f2bf((acc[mi][ni][r] + bv) * 0.18033688f);
        } else {
          #pragma unroll
          for (int r = 0; r < 4; r++)
            Kb[bhb + (size_t)(t0 + r)*HDIM + hd] = f2bf(acc[mi][ni][r] + bv);
        }
      } else {
        const int m = bm + wr*64 + mi*16 + quad*4;
        #pragma unroll
        for (int r = 0; r < 4; r++)
          Out[(size_t)(m + r) * N + n] = acc[mi][ni][r] + bv;
      }
    }
  }
}

// Flash attention v11 (unchanged from round 4): balanced halves, K/V
// double-buffer stage-early, one barrier/tile, T2 swizzle, T5 setprio,
// T12-lite softmax (swapped QK^T + cvt_pk + b64 P-writes).
__global__ __launch_bounds__(256) void attn_kernel(
    const unsigned short* __restrict__ Qb,
    const unsigned short* __restrict__ Kb,
    const unsigned short* __restrict__ Vt,
    unsigned short* __restrict__ Yb)
{
  const int bh   = blockIdx.x;
  const int Gp   = blockIdx.y;                 // 0..7
  const int tid  = threadIdx.x;
  const int wave = tid >> 6;
  const int lane = tid & 63;
  const int quad = lane >> 4;
  const int l16  = lane & 15;

  __shared__ __align__(16) unsigned short Ks[2][64 * 64];   // [buf][key][hd], swz
  __shared__ __align__(16) unsigned short Vs[2][64 * 64];   // [buf][hd][key], swz
  __shared__ __align__(16) unsigned short Pl[8][16][72];    // per-strip P (bf16)

  const unsigned short* __restrict__ qb_ = Qb + (size_t)bh * (SEQ*HDIM);
  const unsigned short* __restrict__ kb_ = Kb + (size_t)bh * (SEQ*HDIM);
  const unsigned short* __restrict__ vb_ = Vt + (size_t)bh * (SEQ*HDIM);
  const int h = bh & (NHEADS - 1);
  const int b = bh >> 4;

  const short ob = (short)0x3F80;    // bf16 1.0
  const bf16x8 ones = {ob,ob,ob,ob,ob,ob,ob,ob};

  const int srow = lane >> 3;                        // 0..7 within 8-row slice
  const int scolswz = ((lane & 7) ^ srow) * 8;       // swizzled 16B slot
  const int krow0 = wave * 16 + srow;                // key-row (K) / hd-row (V) base
  const int xs = (l16 & 7) * 8;                      // read-side XOR (elems)

  auto stage = [&](int buf, int it) {
    const int kb = it * 64;
    #pragma unroll
    for (int j = 0; j < 2; j++)
      load_lds16(kb_ + (size_t)(kb + krow0 + j*8)*HDIM + scolswz,
                 &Ks[buf][wave*1024 + j*512]);
    #pragma unroll
    for (int j = 0; j < 2; j++)
      load_lds16(vb_ + (size_t)(krow0 + j*8)*SEQ + kb + scolswz,
                 &Vs[buf][(wave*16 + j*8)*64]);
  };

  for (int half = 0; half < 2; half++) {
    const int qt = half ? (15 - Gp) : Gp;
    const int nt = 2 * qt + 2;
    const int qs0 = qt * 128 + wave * 32;
    const int myLast = 2 * qt + (wave >> 1);         // last tile this wave needs

    bf16x8 qf[2][2];
    #pragma unroll
    for (int t = 0; t < 2; t++)
      #pragma unroll
      for (int kk = 0; kk < 2; kk++)
        qf[t][kk] = *(const bf16x8*)(qb_ + (qs0 + t*16 + l16)*HDIM + kk*32 + quad*8);

    f32x4 acc[2][4] = {};
    float lrow[2][4] = {};

    stage(0, 0);
    __syncthreads();

    for (int it = 0; it < nt; it++) {
      const int cur = it & 1;

      if (it + 1 < nt) stage(cur ^ 1, it + 1);

      if (it <= myLast) {
        const int kb = it * 64;
        // S^T: swapped operands -> sfr[nf][r] = S[key=kb+nf*16+quad*4+r][q=qs0+strip*16+l16]
        f32x4 sfr[4] = {}, sfr1[4] = {};
        __builtin_amdgcn_s_setprio(1);
        #pragma unroll
        for (int kk = 0; kk < 2; kk++)
          #pragma unroll
          for (int nf = 0; nf < 4; nf++) {
            const bf16x8 kf = *(const bf16x8*)&Ks[cur][(nf*16 + l16)*64 + ((kk*32 + quad*8) ^ xs)];
            sfr[nf]  = __builtin_amdgcn_mfma_f32_16x16x32_bf16(kf, qf[0][kk], sfr[nf], 0, 0, 0);
            sfr1[nf] = __builtin_amdgcn_mfma_f32_16x16x32_bf16(kf, qf[1][kk], sfr1[nf], 0, 0, 0);
          }
        __builtin_amdgcn_s_setprio(0);

        if (it == myLast) {
          #pragma unroll
          for (int nf = 0; nf < 4; nf++) {
            const int key = kb + nf*16 + quad*4;
            #pragma unroll
            for (int r = 0; r < 4; r++) {
              sfr[nf][r]  = (key + r > qs0 + l16)      ? -INFINITY : sfr[nf][r];
              sfr1[nf][r] = (key + r > qs0 + 16 + l16) ? -INFINITY : sfr1[nf][r];
            }
          }
        }

        // P = exp2(S), hw pack, b64 write: Pl[strip][q=l16][k=nf*16+quad*4..+3]
        #pragma unroll
        for (int nf = 0; nf < 4; nf++) {
          uint2 p0, p1;
          p0.x = cvtpk(EXP2(sfr[nf][0]),  EXP2(sfr[nf][1]));
          p0.y = cvtpk(EXP2(sfr[nf][2]),  EXP2(sfr[nf][3]));
          p1.x = cvtpk(EXP2(sfr1[nf][0]), EXP2(sfr1[nf][1]));
          p1.y = cvtpk(EXP2(sfr1[nf][2]), EXP2(sfr1[nf][3]));
          *(uint2*)&Pl[wave*2 + 0][l16][nf*16 + quad*4] = p0;
          *(uint2*)&Pl[wave*2 + 1][l16][nf*16 + quad*4] = p1;
        }

        // PV for both strips
        #pragma unroll
        for (int t = 0; t < 2; t++) {
          f32x4 rsum = {};
          __builtin_amdgcn_s_setprio(1);
          #pragma unroll
          for (int kk = 0; kk < 2; kk++) {
            const bf16x8 pf = *(const bf16x8*)&Pl[wave*2 + t][l16][kk*32 + quad*8];
            #pragma unroll
            for (int nf = 0; nf < 4; nf++) {
              const bf16x8 vf = *(const bf16x8*)&Vs[cur][(nf*16 + l16)*64 + ((kk*32 + quad*8) ^ xs)];
              acc[t][nf] = __builtin_amdgcn_mfma_f32_16x16x32_bf16(pf, vf, acc[t][nf], 0, 0, 0);
            }
            rsum = __builtin_amdgcn_mfma_f32_16x16x32_bf16(pf, ones, rsum, 0, 0, 0);
          }
          __builtin_amdgcn_s_setprio(0);
          #pragma unroll
          for (int r = 0; r < 4; r++) lrow[t][r] += rsum[r];
        }
      }

      __syncthreads();
    }

    // O /= l, write y (B,T,C) bf16
    #pragma unroll
    for (int t = 0; t < 2; t++) {
      #pragma unroll
      for (int r = 0; r < 4; r++) {
        const float inv = 1.0f / lrow[t][r];
        const int trow = qs0 + t*16 + quad*4 + r;
        const size_t off = ((size_t)(b * SEQ + trow)) * D_MODEL + h * HDIM;
        #pragma unroll
        for (int nf = 0; nf < 4; nf++)
          Yb[off + nf*16 + l16] = f2bf(acc[t][nf][r] * inv);
      }
    }
  }
}

extern "C" void kernel_launch(void* const* d_in, const int* in_sizes, int n_in,
                              void* d_out, int out_size, void* d_ws, size_t ws_size,
                              hipStream_t stream) {
  const float* x     = (const float*)d_in[0];
  const float* w_qkv = (const float*)d_in[1];
  const float* b_qkv = (const float*)d_in[2];
  const float* w_out = (const float*)d_in[3];
  const float* b_out = (const float*)d_in[4];
  float* out = (float*)d_out;

  const size_t SZ = (size_t)BATCH * NHEADS * SEQ * HDIM;   // 8M elems
  unsigned short* Qb  = (unsigned short*)d_ws;             // 16 MiB
  unsigned short* Kb  = Qb + SZ;                           // 16 MiB
  unsigned short* Vb  = Kb + SZ;                           // 16 MiB (V^T)
  unsigned short* Xb  = Vb + SZ;                           // 16 MiB, aliased by Yb
  unsigned short* Yb  = Xb;                                // attn writes after gemm0 reads
  unsigned short* WqT = Xb + SZ;                           // 6 MiB
  unsigned short* WoT = WqT + (size_t)3*D_MODEL*D_MODEL;   // 2 MiB

  prep_kernel<<<dim3(4096 + 768 + 256), 256, 0, stream>>>(
      x, Xb, w_qkv, WqT, w_out, WoT);

  gemm_db<0><<<dim3(3*D_MODEL/256, BATCH*SEQ/128), 512, 0, stream>>>(
      Xb, WqT, b_qkv, Qb, Kb, Vb, nullptr);
  attn_kernel<<<dim3(BATCH*NHEADS, 8), 256, 0, stream>>>(Qb, Kb, Vb, Yb);
  gemm_db<1><<<dim3(D_MODEL/256, BATCH*SEQ/128), 512, 0, stream>>>(
      Yb, WoT, b_out, nullptr, nullptr, nullptr, out);
}

// Round 7
// 237.821 us; speedup vs baseline: 1.1469x; 1.0319x over previous
//
#include <hip/hip_runtime.h>
#include <hip/hip_bf16.h>
#include <math.h>

#define D_MODEL 1024
#define NHEADS  16
#define HDIM    64
#define BATCH   4
#define SEQ     2048

typedef __attribute__((ext_vector_type(8))) short bf16x8;
typedef __attribute__((ext_vector_type(4))) float f32x4;

#if __has_builtin(__builtin_amdgcn_exp2f)
#define EXP2(x) __builtin_amdgcn_exp2f(x)
#else
#define EXP2(x) exp2f(x)
#endif

__device__ __forceinline__ unsigned short f2bf(float f) {
  union { float f; unsigned u; } v; v.f = f;
  unsigned r = v.u + 0x7FFFu + ((v.u >> 16) & 1u);   // RNE
  return (unsigned short)(r >> 16);
}

// pack 2 f32 -> 2 bf16 in one dword (RNE), hw instruction (no builtin, m240)
__device__ __forceinline__ unsigned cvtpk(float lo, float hi) {
  unsigned r;
  asm("v_cvt_pk_bf16_f32 %0, %1, %2" : "=v"(r) : "v"(lo), "v"(hi));
  return r;
}

__device__ __forceinline__ void load_lds16(const unsigned short* g, unsigned short* l) {
  __builtin_amdgcn_global_load_lds(
      (const __attribute__((address_space(1))) unsigned int*)g,
      (__attribute__((address_space(3))) unsigned int*)l, 16, 0, 0);
}

// ---- fused pre-pass: x cast (blocks 0..4095), w_qkv transpose (4096..4863),
//      w_out transpose (4864..5119). ----
__global__ __launch_bounds__(256) void prep_kernel(
    const float* __restrict__ x,     unsigned short* __restrict__ Xb,
    const float* __restrict__ w_qkv, unsigned short* __restrict__ WqT,
    const float* __restrict__ w_out, unsigned short* __restrict__ WoT)
{
  __shared__ float t[64][65];
  const int id  = blockIdx.x;
  const int tid = threadIdx.x;

  if (id < 4096) {                       // ---- cast chunk ----
    const int idx = (id * 256 + tid) * 8;
    float4 a = *(const float4*)&x[idx];
    float4 b = *(const float4*)&x[idx + 4];
    alignas(16) unsigned short o[8] = {
      f2bf(a.x), f2bf(a.y), f2bf(a.z), f2bf(a.w),
      f2bf(b.x), f2bf(b.y), f2bf(b.z), f2bf(b.w)};
    *(uint4*)&Xb[idx] = *(uint4*)o;
    return;
  }

  // ---- transpose_cast: W [1024][N] fp32 -> WT [N][1024] bf16 ----
  const float* W; unsigned short* WT; int N, rblk;
  if (id < 4096 + 768) { W = w_qkv; WT = WqT; N = 3 * D_MODEL; rblk = id - 4096; }
  else                 { W = w_out; WT = WoT; N = D_MODEL;     rblk = id - 4864; }
  const int gx = N / 64;
  const int n0 = (rblk % gx) * 64, k0 = (rblk / gx) * 64;
  const int r = tid >> 2, c0 = (tid & 3) * 16;
  #pragma unroll
  for (int i = 0; i < 16; i += 4) {
    float4 f = *(const float4*)&W[(size_t)(k0 + r) * N + n0 + c0 + i];
    t[r][c0+i] = f.x; t[r][c0+i+1] = f.y; t[r][c0+i+2] = f.z; t[r][c0+i+3] = f.w;
  }
  __syncthreads();
  #pragma unroll
  for (int i = 0; i < 16; i += 4) {
    alignas(8) unsigned short s[4] = {
      f2bf(t[c0+i][r]), f2bf(t[c0+i+1][r]), f2bf(t[c0+i+2][r]), f2bf(t[c0+i+3][r])};
    *(uint2*)&WT[(size_t)(n0 + r) * 1024 + k0 + c0 + i] = *(uint2*)s;
  }
}

// ---- 128x256-tile double-buffered GEMM (unchanged from round 5) ----
template<int MODE>
__global__ __launch_bounds__(512, 2) void gemm_db(
    const unsigned short* __restrict__ A,
    const unsigned short* __restrict__ Bt,
    const float* __restrict__ bias,
    unsigned short* __restrict__ Qb, unsigned short* __restrict__ Kb,
    unsigned short* __restrict__ Vb, float* __restrict__ Out)
{
  constexpr int N   = (MODE == 0) ? 3 * D_MODEL : D_MODEL;
  constexpr int NT  = D_MODEL / 64;                // 16 K-tiles
  constexpr int GX  = N / 256;                     // 12 or 4
  constexpr int NWG = GX * (BATCH * SEQ / 128);    // 768 or 256 (both %8==0)

  int id = blockIdx.y * GX + blockIdx.x;
  id = (id & 7) * (NWG >> 3) + (id >> 3);          // T1 bijective XCD swizzle
  const int bn = (id % GX) * 256;
  const int bm = (id / GX) * 128;

  const int tid  = threadIdx.x;
  const int lane = tid & 63;
  const int w    = tid >> 6;
  const int quad = lane >> 4;
  const int l16  = lane & 15;
  const int wr = w >> 2, wc = w & 3;

  __shared__ __align__(16) unsigned short lds[49152];   // 96 KiB

  const int srow = lane >> 3;
  const int scol = ((lane & 7) ^ srow) * 8;
  const unsigned short* __restrict__ Ag = A  + (size_t)(bm + w*8 + srow) * D_MODEL + scol;
  const unsigned short* __restrict__ Bg = Bt + (size_t)(bn + w*8 + srow) * D_MODEL + scol;
  const int xs = (l16 & 7) * 8;

  f32x4 acc[4][4] = {};

  auto stageAll = [&](int buf, int t2) {
    unsigned short* dA = &lds[buf*8192 + w*512];
    unsigned short* dB = &lds[16384 + buf*16384 + w*512];
    const unsigned short* gA = Ag + t2*64;
    const unsigned short* gB = Bg + t2*64;
    load_lds16(gA,                      dA);
    load_lds16(gA + (size_t)64*D_MODEL, dA + 4096);
    #pragma unroll
    for (int c = 0; c < 4; c++)
      load_lds16(gB + (size_t)c*64*D_MODEL, dB + c*4096);
  };
  auto rdA = [&](int buf, int mi, int kk) {
    return *(const bf16x8*)&lds[buf*8192 +
        (wr*64 + mi*16 + l16)*64 + (((kk*4 + quad)*8) ^ xs)];
  };
  auto rdB = [&](int buf, int ni, int kk) {
    return *(const bf16x8*)&lds[16384 + buf*16384 +
        (wc*64 + ni*16 + l16)*64 + (((kk*4 + quad)*8) ^ xs)];
  };

  stageAll(0, 0);
  __syncthreads();

  for (int t = 0; t < NT; ++t) {
    const int cur = t & 1;
    if (t + 1 < NT) stageAll(cur ^ 1, t + 1);

    #pragma unroll
    for (int kk = 0; kk < 2; kk++) {
      bf16x8 af[4], bfv[4];
      #pragma unroll
      for (int mi = 0; mi < 4; mi++) af[mi]  = rdA(cur, mi, kk);
      #pragma unroll
      for (int ni = 0; ni < 4; ni++) bfv[ni] = rdB(cur, ni, kk);
      __builtin_amdgcn_s_setprio(1);
      #pragma unroll
      for (int mi = 0; mi < 4; mi++)
        #pragma unroll
        for (int ni = 0; ni < 4; ni++)
          acc[mi][ni] = __builtin_amdgcn_mfma_f32_16x16x32_bf16(af[mi], bfv[ni], acc[mi][ni], 0, 0, 0);
      __builtin_amdgcn_s_setprio(0);
    }

    __syncthreads();
  }

  const int b   = bm >> 11;
  const int tl0 = (bm & (SEQ - 1));
  #pragma unroll
  for (int ni = 0; ni < 4; ni++) {
    const int n = bn + wc*64 + ni*16 + l16;
    const float bv = bias[n];
    #pragma unroll
    for (int mi = 0; mi < 4; mi++) {
      const int t0 = tl0 + wr*64 + mi*16 + quad*4;
      if (MODE == 0) {
        const int which = n >> 10;
        const int c = n & 1023;
        const int h = c >> 6, hd = c & 63;
        const size_t bhb = ((size_t)(b*NHEADS + h)) * (SEQ*HDIM);
        if (which == 2) {
          alignas(8) unsigned short pk[4];
          #pragma unroll
          for (int r = 0; r < 4; r++) pk[r] = f2bf(acc[mi][ni][r] + bv);
          *(uint2*)&Vb[bhb + (size_t)hd*SEQ + t0] = *(uint2*)pk;
        } else if (which == 0) {
          #pragma unroll
          for (int r = 0; r < 4; r++)
            Qb[bhb + (size_t)(t0 + r)*HDIM + hd] = f2bf((acc[mi][ni][r] + bv) * 0.18033688f);
        } else {
          #pragma unroll
          for (int r = 0; r < 4; r++)
            Kb[bhb + (size_t)(t0 + r)*HDIM + hd] = f2bf(acc[mi][ni][r] + bv);
        }
      } else {
        const int m = bm + wr*64 + mi*16 + quad*4;
        #pragma unroll
        for (int r = 0; r < 4; r++)
          Out[(size_t)(m + r) * N + n] = acc[mi][ni][r] + bv;
      }
    }
  }
}

// Flash attention v13: one q-tile per block (grid 64x16, heavy-first
// qt = 15 - blockIdx.y), K/V double-buffer stage-early, one barrier/tile,
// T2 swizzle, T5 setprio, T12-lite softmax. PV loop reverted VERBATIM to
// v11's per-strip form (round-5 passing) — round-6's V-hoist removed
// (prime suspect for the absmax failure: new read/MFMA code shape).
__global__ __launch_bounds__(256) void attn_kernel(
    const unsigned short* __restrict__ Qb,
    const unsigned short* __restrict__ Kb,
    const unsigned short* __restrict__ Vt,
    unsigned short* __restrict__ Yb)
{
  const int bh   = blockIdx.x;
  const int qt   = 15 - blockIdx.y;            // heavy blocks dispatch first
  const int tid  = threadIdx.x;
  const int wave = tid >> 6;
  const int lane = tid & 63;
  const int quad = lane >> 4;
  const int l16  = lane & 15;

  __shared__ __align__(16) unsigned short Ks[2][64 * 64];   // [buf][key][hd], swz
  __shared__ __align__(16) unsigned short Vs[2][64 * 64];   // [buf][hd][key], swz
  __shared__ __align__(16) unsigned short Pl[8][16][72];    // per-strip P (bf16)

  const unsigned short* __restrict__ qb_ = Qb + (size_t)bh * (SEQ*HDIM);
  const unsigned short* __restrict__ kb_ = Kb + (size_t)bh * (SEQ*HDIM);
  const unsigned short* __restrict__ vb_ = Vt + (size_t)bh * (SEQ*HDIM);
  const int h = bh & (NHEADS - 1);
  const int b = bh >> 4;

  const short ob = (short)0x3F80;    // bf16 1.0
  const bf16x8 ones = {ob,ob,ob,ob,ob,ob,ob,ob};

  const int srow = lane >> 3;                        // 0..7 within 8-row slice
  const int scolswz = ((lane & 7) ^ srow) * 8;       // swizzled 16B slot
  const int krow0 = wave * 16 + srow;                // key-row (K) / hd-row (V) base
  const int xs = (l16 & 7) * 8;                      // read-side XOR (elems)

  auto stage = [&](int buf, int it) {
    const int kb = it * 64;
    #pragma unroll
    for (int j = 0; j < 2; j++)
      load_lds16(kb_ + (size_t)(kb + krow0 + j*8)*HDIM + scolswz,
                 &Ks[buf][wave*1024 + j*512]);
    #pragma unroll
    for (int j = 0; j < 2; j++)
      load_lds16(vb_ + (size_t)(krow0 + j*8)*SEQ + kb + scolswz,
                 &Vs[buf][(wave*16 + j*8)*64]);
  };

  const int nt = 2 * qt + 2;
  const int qs0 = qt * 128 + wave * 32;
  const int myLast = 2 * qt + (wave >> 1);           // last tile this wave needs

  bf16x8 qf[2][2];
  #pragma unroll
  for (int t = 0; t < 2; t++)
    #pragma unroll
    for (int kk = 0; kk < 2; kk++)
      qf[t][kk] = *(const bf16x8*)(qb_ + (qs0 + t*16 + l16)*HDIM + kk*32 + quad*8);

  f32x4 acc[2][4] = {};
  float lrow[2][4] = {};

  stage(0, 0);
  __syncthreads();

  for (int it = 0; it < nt; it++) {
    const int cur = it & 1;

    if (it + 1 < nt) stage(cur ^ 1, it + 1);

    if (it <= myLast) {
      const int kb = it * 64;
      // S^T: swapped operands -> sfr[nf][r] = S[key=kb+nf*16+quad*4+r][q=qs0+strip*16+l16]
      f32x4 sfr[4] = {}, sfr1[4] = {};
      __builtin_amdgcn_s_setprio(1);
      #pragma unroll
      for (int kk = 0; kk < 2; kk++)
        #pragma unroll
        for (int nf = 0; nf < 4; nf++) {
          const bf16x8 kf = *(const bf16x8*)&Ks[cur][(nf*16 + l16)*64 + ((kk*32 + quad*8) ^ xs)];
          sfr[nf]  = __builtin_amdgcn_mfma_f32_16x16x32_bf16(kf, qf[0][kk], sfr[nf], 0, 0, 0);
          sfr1[nf] = __builtin_amdgcn_mfma_f32_16x16x32_bf16(kf, qf[1][kk], sfr1[nf], 0, 0, 0);
        }
      __builtin_amdgcn_s_setprio(0);

      if (it == myLast) {
        #pragma unroll
        for (int nf = 0; nf < 4; nf++) {
          const int key = kb + nf*16 + quad*4;
          #pragma unroll
          for (int r = 0; r < 4; r++) {
            sfr[nf][r]  = (key + r > qs0 + l16)      ? -INFINITY : sfr[nf][r];
            sfr1[nf][r] = (key + r > qs0 + 16 + l16) ? -INFINITY : sfr1[nf][r];
          }
        }
      }

      // P = exp2(S), hw pack, b64 write: Pl[strip][q=l16][k=nf*16+quad*4..+3]
      #pragma unroll
      for (int nf = 0; nf < 4; nf++) {
        uint2 p0, p1;
        p0.x = cvtpk(EXP2(sfr[nf][0]),  EXP2(sfr[nf][1]));
        p0.y = cvtpk(EXP2(sfr[nf][2]),  EXP2(sfr[nf][3]));
        p1.x = cvtpk(EXP2(sfr1[nf][0]), EXP2(sfr1[nf][1]));
        p1.y = cvtpk(EXP2(sfr1[nf][2]), EXP2(sfr1[nf][3]));
        *(uint2*)&Pl[wave*2 + 0][l16][nf*16 + quad*4] = p0;
        *(uint2*)&Pl[wave*2 + 1][l16][nf*16 + quad*4] = p1;
      }

      // PV for both strips — v11-verbatim (per-strip V-frag reads)
      #pragma unroll
      for (int t = 0; t < 2; t++) {
        f32x4 rsum = {};
        __builtin_amdgcn_s_setprio(1);
        #pragma unroll
        for (int kk = 0; kk < 2; kk++) {
          const bf16x8 pf = *(const bf16x8*)&Pl[wave*2 + t][l16][kk*32 + quad*8];
          #pragma unroll
          for (int nf = 0; nf < 4; nf++) {
            const bf16x8 vf = *(const bf16x8*)&Vs[cur][(nf*16 + l16)*64 + ((kk*32 + quad*8) ^ xs)];
            acc[t][nf] = __builtin_amdgcn_mfma_f32_16x16x32_bf16(pf, vf, acc[t][nf], 0, 0, 0);
          }
          rsum = __builtin_amdgcn_mfma_f32_16x16x32_bf16(pf, ones, rsum, 0, 0, 0);
        }
        __builtin_amdgcn_s_setprio(0);
        #pragma unroll
        for (int r = 0; r < 4; r++) lrow[t][r] += rsum[r];
      }
    }

    __syncthreads();   // drains staging (issued a full tile earlier) + protects bufs
  }

  // O /= l, write y (B,T,C) bf16
  #pragma unroll
  for (int t = 0; t < 2; t++) {
    #pragma unroll
    for (int r = 0; r < 4; r++) {
      const float inv = 1.0f / lrow[t][r];
      const int trow = qs0 + t*16 + quad*4 + r;
      const size_t off = ((size_t)(b * SEQ + trow)) * D_MODEL + h * HDIM;
      #pragma unroll
      for (int nf = 0; nf < 4; nf++)
        Yb[off + nf*16 + l16] = f2bf(acc[t][nf][r] * inv);
    }
  }
}

extern "C" void kernel_launch(void* const* d_in, const int* in_sizes, int n_in,
                              void* d_out, int out_size, void* d_ws, size_t ws_size,
                              hipStream_t stream) {
  const float* x     = (const float*)d_in[0];
  const float* w_qkv = (const float*)d_in[1];
  const float* b_qkv = (const float*)d_in[2];
  const float* w_out = (const float*)d_in[3];
  const float* b_out = (const float*)d_in[4];
  float* out = (float*)d_out;

  const size_t SZ = (size_t)BATCH * NHEADS * SEQ * HDIM;   // 8M elems
  unsigned short* Qb  = (unsigned short*)d_ws;             // 16 MiB
  unsigned short* Kb  = Qb + SZ;                           // 16 MiB
  unsigned short* Vb  = Kb + SZ;                           // 16 MiB (V^T)
  unsigned short* Xb  = Vb + SZ;                           // 16 MiB, aliased by Yb
  unsigned short* Yb  = Xb;                                // attn writes after gemm0 reads
  unsigned short* WqT = Xb + SZ;                           // 6 MiB
  unsigned short* WoT = WqT + (size_t)3*D_MODEL*D_MODEL;   // 2 MiB

  prep_kernel<<<dim3(4096 + 768 + 256), 256, 0, stream>>>(
      x, Xb, w_qkv, WqT, w_out, WoT);

  gemm_db<0><<<dim3(3*D_MODEL/256, BATCH*SEQ/128), 512, 0, stream>>>(
      Xb, WqT, b_qkv, Qb, Kb, Vb, nullptr);
  attn_kernel<<<dim3(BATCH*NHEADS, 16), 256, 0, stream>>>(Qb, Kb, Vb, Yb);
  gemm_db<1><<<dim3(D_MODEL/256, BATCH*SEQ/128), 512, 0, stream>>>(
      Yb, WoT, b_out, nullptr, nullptr, nullptr, out);
}

// Round 8
// 225.506 us; speedup vs baseline: 1.2095x; 1.0546x over previous
//
#include <hip/hip_runtime.h>
#include <hip/hip_bf16.h>
#include <math.h>

#define D_MODEL 1024
#define NHEADS  16
#define HDIM    64
#define BATCH   4
#define SEQ     2048

typedef __attribute__((ext_vector_type(8))) short bf16x8;
typedef __attribute__((ext_vector_type(4))) float f32x4;

#if __has_builtin(__builtin_amdgcn_exp2f)
#define EXP2(x) __builtin_amdgcn_exp2f(x)
#else
#define EXP2(x) exp2f(x)
#endif

__device__ __forceinline__ unsigned short f2bf(float f) {
  union { float f; unsigned u; } v; v.f = f;
  unsigned r = v.u + 0x7FFFu + ((v.u >> 16) & 1u);   // RNE
  return (unsigned short)(r >> 16);
}

// pack 2 f32 -> 2 bf16 in one dword (RNE), hw instruction (no builtin, m240)
__device__ __forceinline__ unsigned cvtpk(float lo, float hi) {
  unsigned r;
  asm("v_cvt_pk_bf16_f32 %0, %1, %2" : "=v"(r) : "v"(lo), "v"(hi));
  return r;
}

__device__ __forceinline__ void load_lds16(const unsigned short* g, unsigned short* l) {
  __builtin_amdgcn_global_load_lds(
      (const __attribute__((address_space(1))) unsigned int*)g,
      (__attribute__((address_space(3))) unsigned int*)l, 16, 0, 0);
}

// ---- fused pre-pass: x cast (blocks 0..4095), w_qkv transpose (4096..4863),
//      w_out transpose (4864..5119). ----
__global__ __launch_bounds__(256) void prep_kernel(
    const float* __restrict__ x,     unsigned short* __restrict__ Xb,
    const float* __restrict__ w_qkv, unsigned short* __restrict__ WqT,
    const float* __restrict__ w_out, unsigned short* __restrict__ WoT)
{
  __shared__ float t[64][65];
  const int id  = blockIdx.x;
  const int tid = threadIdx.x;

  if (id < 4096) {                       // ---- cast chunk ----
    const int idx = (id * 256 + tid) * 8;
    float4 a = *(const float4*)&x[idx];
    float4 b = *(const float4*)&x[idx + 4];
    alignas(16) unsigned short o[8] = {
      f2bf(a.x), f2bf(a.y), f2bf(a.z), f2bf(a.w),
      f2bf(b.x), f2bf(b.y), f2bf(b.z), f2bf(b.w)};
    *(uint4*)&Xb[idx] = *(uint4*)o;
    return;
  }

  // ---- transpose_cast: W [1024][N] fp32 -> WT [N][1024] bf16 ----
  const float* W; unsigned short* WT; int N, rblk;
  if (id < 4096 + 768) { W = w_qkv; WT = WqT; N = 3 * D_MODEL; rblk = id - 4096; }
  else                 { W = w_out; WT = WoT; N = D_MODEL;     rblk = id - 4864; }
  const int gx = N / 64;
  const int n0 = (rblk % gx) * 64, k0 = (rblk / gx) * 64;
  const int r = tid >> 2, c0 = (tid & 3) * 16;
  #pragma unroll
  for (int i = 0; i < 16; i += 4) {
    float4 f = *(const float4*)&W[(size_t)(k0 + r) * N + n0 + c0 + i];
    t[r][c0+i] = f.x; t[r][c0+i+1] = f.y; t[r][c0+i+2] = f.z; t[r][c0+i+3] = f.w;
  }
  __syncthreads();
  #pragma unroll
  for (int i = 0; i < 16; i += 4) {
    alignas(8) unsigned short s[4] = {
      f2bf(t[c0+i][r]), f2bf(t[c0+i+1][r]), f2bf(t[c0+i+2][r]), f2bf(t[c0+i+3][r])};
    *(uint2*)&WT[(size_t)(n0 + r) * 1024 + k0 + c0 + i] = *(uint2*)s;
  }
}

// ---- 128x128-tile double-buffered GEMM: 4 waves (2x2), per-wave 64x64.
// LDS 64 KiB -> 2 blocks/CU: two independent barrier groups per CU (the
// round-7 lesson: 1-blk/CU lockstep was the wall, not barrier count).
// Same dbuf stage-early 1-barrier structure, T2 swizzle, T5 setprio,
// T1 bijective XCD swizzle.
template<int MODE>
__global__ __launch_bounds__(256, 2) void gemm_db(
    const unsigned short* __restrict__ A,
    const unsigned short* __restrict__ Bt,
    const float* __restrict__ bias,
    unsigned short* __restrict__ Qb, unsigned short* __restrict__ Kb,
    unsigned short* __restrict__ Vb, float* __restrict__ Out)
{
  constexpr int N   = (MODE == 0) ? 3 * D_MODEL : D_MODEL;
  constexpr int NT  = D_MODEL / 64;                // 16 K-tiles
  constexpr int GX  = N / 128;                     // 24 or 8
  constexpr int NWG = GX * (BATCH * SEQ / 128);    // 1536 or 512 (both %8==0)

  int id = blockIdx.y * GX + blockIdx.x;
  id = (id & 7) * (NWG >> 3) + (id >> 3);          // T1 bijective XCD swizzle
  const int bn = (id % GX) * 128;
  const int bm = (id / GX) * 128;

  const int tid  = threadIdx.x;
  const int lane = tid & 63;
  const int w    = tid >> 6;                       // 0..3
  const int quad = lane >> 4;
  const int l16  = lane & 15;
  const int wr = w >> 1, wc = w & 1;

  // A: [2][128][64] @ 0, B: [2][128][64] @ 16384 (elems); total 64 KiB
  __shared__ __align__(16) unsigned short lds[32768];

  // staging: linear LDS dest, swizzle on per-lane GLOBAL source (rule 21)
  const int srow = lane >> 3;
  const int scol = ((lane & 7) ^ srow) * 8;
  const unsigned short* __restrict__ Ag = A  + (size_t)(bm + w*32 + srow) * D_MODEL + scol;
  const unsigned short* __restrict__ Bg = Bt + (size_t)(bn + w*32 + srow) * D_MODEL + scol;
  const int xs = (l16 & 7) * 8;                    // read-side XOR (elems)

  f32x4 acc[4][4] = {};

  auto stageAll = [&](int buf, int t2) {           // 8 loads/wave (4 A + 4 B)
    unsigned short* dA = &lds[buf*8192 + w*2048];
    unsigned short* dB = &lds[16384 + buf*8192 + w*2048];
    const unsigned short* gA = Ag + t2*64;
    const unsigned short* gB = Bg + t2*64;
    #pragma unroll
    for (int c = 0; c < 4; c++) {
      load_lds16(gA + (size_t)c*8*D_MODEL, dA + c*512);
      load_lds16(gB + (size_t)c*8*D_MODEL, dB + c*512);
    }
  };
  auto rdA = [&](int buf, int mi, int kk) {
    return *(const bf16x8*)&lds[buf*8192 +
        (wr*64 + mi*16 + l16)*64 + (((kk*4 + quad)*8) ^ xs)];
  };
  auto rdB = [&](int buf, int ni, int kk) {
    return *(const bf16x8*)&lds[16384 + buf*8192 +
        (wc*64 + ni*16 + l16)*64 + (((kk*4 + quad)*8) ^ xs)];
  };

  stageAll(0, 0);
  __syncthreads();                                  // tile 0 ready

  for (int t = 0; t < NT; ++t) {
    const int cur = t & 1;
    if (t + 1 < NT) stageAll(cur ^ 1, t + 1);       // issue-early

    #pragma unroll
    for (int kk = 0; kk < 2; kk++) {
      bf16x8 af[4], bfv[4];
      #pragma unroll
      for (int mi = 0; mi < 4; mi++) af[mi]  = rdA(cur, mi, kk);
      #pragma unroll
      for (int ni = 0; ni < 4; ni++) bfv[ni] = rdB(cur, ni, kk);
      __builtin_amdgcn_s_setprio(1);
      #pragma unroll
      for (int mi = 0; mi < 4; mi++)
        #pragma unroll
        for (int ni = 0; ni < 4; ni++)
          acc[mi][ni] = __builtin_amdgcn_mfma_f32_16x16x32_bf16(af[mi], bfv[ni], acc[mi][ni], 0, 0, 0);
      __builtin_amdgcn_s_setprio(0);
    }

    __syncthreads();   // drains staging (issued at tile top) + protects bufs
  }

  // ---- epilogue (per-wave tile = 64x64) ----
  const int b   = bm >> 11;
  const int tl0 = (bm & (SEQ - 1));
  #pragma unroll
  for (int ni = 0; ni < 4; ni++) {
    const int n = bn + wc*64 + ni*16 + l16;
    const float bv = bias[n];
    #pragma unroll
    for (int mi = 0; mi < 4; mi++) {
      const int t0 = tl0 + wr*64 + mi*16 + quad*4;
      if (MODE == 0) {
        const int which = n >> 10;
        const int c = n & 1023;
        const int h = c >> 6, hd = c & 63;
        const size_t bhb = ((size_t)(b*NHEADS + h)) * (SEQ*HDIM);
        if (which == 2) {
          alignas(8) unsigned short pk[4];
          #pragma unroll
          for (int r = 0; r < 4; r++) pk[r] = f2bf(acc[mi][ni][r] + bv);
          *(uint2*)&Vb[bhb + (size_t)hd*SEQ + t0] = *(uint2*)pk;
        } else if (which == 0) {
          #pragma unroll
          for (int r = 0; r < 4; r++)
            Qb[bhb + (size_t)(t0 + r)*HDIM + hd] = f2bf((acc[mi][ni][r] + bv) * 0.18033688f);
        } else {
          #pragma unroll
          for (int r = 0; r < 4; r++)
            Kb[bhb + (size_t)(t0 + r)*HDIM + hd] = f2bf(acc[mi][ni][r] + bv);
        }
      } else {
        const int m = bm + wr*64 + mi*16 + quad*4;
        #pragma unroll
        for (int r = 0; r < 4; r++)
          Out[(size_t)(m + r) * N + n] = acc[mi][ni][r] + bv;
      }
    }
  }
}

// Flash attention v13 (unchanged, round-7 passing): one q-tile per block
// (grid 64x16, heavy-first), K/V double-buffer stage-early, one barrier/tile,
// T2 swizzle, T5 setprio, T12-lite softmax (swapped QK^T + cvt_pk + b64).
__global__ __launch_bounds__(256) void attn_kernel(
    const unsigned short* __restrict__ Qb,
    const unsigned short* __restrict__ Kb,
    const unsigned short* __restrict__ Vt,
    unsigned short* __restrict__ Yb)
{
  const int bh   = blockIdx.x;
  const int qt   = 15 - blockIdx.y;            // heavy blocks dispatch first
  const int tid  = threadIdx.x;
  const int wave = tid >> 6;
  const int lane = tid & 63;
  const int quad = lane >> 4;
  const int l16  = lane & 15;

  __shared__ __align__(16) unsigned short Ks[2][64 * 64];   // [buf][key][hd], swz
  __shared__ __align__(16) unsigned short Vs[2][64 * 64];   // [buf][hd][key], swz
  __shared__ __align__(16) unsigned short Pl[8][16][72];    // per-strip P (bf16)

  const unsigned short* __restrict__ qb_ = Qb + (size_t)bh * (SEQ*HDIM);
  const unsigned short* __restrict__ kb_ = Kb + (size_t)bh * (SEQ*HDIM);
  const unsigned short* __restrict__ vb_ = Vt + (size_t)bh * (SEQ*HDIM);
  const int h = bh & (NHEADS - 1);
  const int b = bh >> 4;

  const short ob = (short)0x3F80;    // bf16 1.0
  const bf16x8 ones = {ob,ob,ob,ob,ob,ob,ob,ob};

  const int srow = lane >> 3;                        // 0..7 within 8-row slice
  const int scolswz = ((lane & 7) ^ srow) * 8;       // swizzled 16B slot
  const int krow0 = wave * 16 + srow;                // key-row (K) / hd-row (V) base
  const int xs = (l16 & 7) * 8;                      // read-side XOR (elems)

  auto stage = [&](int buf, int it) {
    const int kb = it * 64;
    #pragma unroll
    for (int j = 0; j < 2; j++)
      load_lds16(kb_ + (size_t)(kb + krow0 + j*8)*HDIM + scolswz,
                 &Ks[buf][wave*1024 + j*512]);
    #pragma unroll
    for (int j = 0; j < 2; j++)
      load_lds16(vb_ + (size_t)(krow0 + j*8)*SEQ + kb + scolswz,
                 &Vs[buf][(wave*16 + j*8)*64]);
  };

  const int nt = 2 * qt + 2;
  const int qs0 = qt * 128 + wave * 32;
  const int myLast = 2 * qt + (wave >> 1);           // last tile this wave needs

  bf16x8 qf[2][2];
  #pragma unroll
  for (int t = 0; t < 2; t++)
    #pragma unroll
    for (int kk = 0; kk < 2; kk++)
      qf[t][kk] = *(const bf16x8*)(qb_ + (qs0 + t*16 + l16)*HDIM + kk*32 + quad*8);

  f32x4 acc[2][4] = {};
  float lrow[2][4] = {};

  stage(0, 0);
  __syncthreads();

  for (int it = 0; it < nt; it++) {
    const int cur = it & 1;

    if (it + 1 < nt) stage(cur ^ 1, it + 1);

    if (it <= myLast) {
      const int kb = it * 64;
      // S^T: swapped operands -> sfr[nf][r] = S[key=kb+nf*16+quad*4+r][q=qs0+strip*16+l16]
      f32x4 sfr[4] = {}, sfr1[4] = {};
      __builtin_amdgcn_s_setprio(1);
      #pragma unroll
      for (int kk = 0; kk < 2; kk++)
        #pragma unroll
        for (int nf = 0; nf < 4; nf++) {
          const bf16x8 kf = *(const bf16x8*)&Ks[cur][(nf*16 + l16)*64 + ((kk*32 + quad*8) ^ xs)];
          sfr[nf]  = __builtin_amdgcn_mfma_f32_16x16x32_bf16(kf, qf[0][kk], sfr[nf], 0, 0, 0);
          sfr1[nf] = __builtin_amdgcn_mfma_f32_16x16x32_bf16(kf, qf[1][kk], sfr1[nf], 0, 0, 0);
        }
      __builtin_amdgcn_s_setprio(0);

      if (it == myLast) {
        #pragma unroll
        for (int nf = 0; nf < 4; nf++) {
          const int key = kb + nf*16 + quad*4;
          #pragma unroll
          for (int r = 0; r < 4; r++) {
            sfr[nf][r]  = (key + r > qs0 + l16)      ? -INFINITY : sfr[nf][r];
            sfr1[nf][r] = (key + r > qs0 + 16 + l16) ? -INFINITY : sfr1[nf][r];
          }
        }
      }

      // P = exp2(S), hw pack, b64 write: Pl[strip][q=l16][k=nf*16+quad*4..+3]
      #pragma unroll
      for (int nf = 0; nf < 4; nf++) {
        uint2 p0, p1;
        p0.x = cvtpk(EXP2(sfr[nf][0]),  EXP2(sfr[nf][1]));
        p0.y = cvtpk(EXP2(sfr[nf][2]),  EXP2(sfr[nf][3]));
        p1.x = cvtpk(EXP2(sfr1[nf][0]), EXP2(sfr1[nf][1]));
        p1.y = cvtpk(EXP2(sfr1[nf][2]), EXP2(sfr1[nf][3]));
        *(uint2*)&Pl[wave*2 + 0][l16][nf*16 + quad*4] = p0;
        *(uint2*)&Pl[wave*2 + 1][l16][nf*16 + quad*4] = p1;
      }

      // PV for both strips — v11-verbatim (per-strip V-frag reads)
      #pragma unroll
      for (int t = 0; t < 2; t++) {
        f32x4 rsum = {};
        __builtin_amdgcn_s_setprio(1);
        #pragma unroll
        for (int kk = 0; kk < 2; kk++) {
          const bf16x8 pf = *(const bf16x8*)&Pl[wave*2 + t][l16][kk*32 + quad*8];
          #pragma unroll
          for (int nf = 0; nf < 4; nf++) {
            const bf16x8 vf = *(const bf16x8*)&Vs[cur][(nf*16 + l16)*64 + ((kk*32 + quad*8) ^ xs)];
            acc[t][nf] = __builtin_amdgcn_mfma_f32_16x16x32_bf16(pf, vf, acc[t][nf], 0, 0, 0);
          }
          rsum = __builtin_amdgcn_mfma_f32_16x16x32_bf16(pf, ones, rsum, 0, 0, 0);
        }
        __builtin_amdgcn_s_setprio(0);
        #pragma unroll
        for (int r = 0; r < 4; r++) lrow[t][r] += rsum[r];
      }
    }

    __syncthreads();   // drains staging (issued a full tile earlier) + protects bufs
  }

  // O /= l, write y (B,T,C) bf16
  #pragma unroll
  for (int t = 0; t < 2; t++) {
    #pragma unroll
    for (int r = 0; r < 4; r++) {
      const float inv = 1.0f / lrow[t][r];
      const int trow = qs0 + t*16 + quad*4 + r;
      const size_t off = ((size_t)(b * SEQ + trow)) * D_MODEL + h * HDIM;
      #pragma unroll
      for (int nf = 0; nf < 4; nf++)
        Yb[off + nf*16 + l16] = f2bf(acc[t][nf][r] * inv);
    }
  }
}

extern "C" void kernel_launch(void* const* d_in, const int* in_sizes, int n_in,
                              void* d_out, int out_size, void* d_ws, size_t ws_size,
                              hipStream_t stream) {
  const float* x     = (const float*)d_in[0];
  const float* w_qkv = (const float*)d_in[1];
  const float* b_qkv = (const float*)d_in[2];
  const float* w_out = (const float*)d_in[3];
  const float* b_out = (const float*)d_in[4];
  float* out = (float*)d_out;

  const size_t SZ = (size_t)BATCH * NHEADS * SEQ * HDIM;   // 8M elems
  unsigned short* Qb  = (unsigned short*)d_ws;             // 16 MiB
  unsigned short* Kb  = Qb + SZ;                           // 16 MiB
  unsigned short* Vb  = Kb + SZ;                           // 16 MiB (V^T)
  unsigned short* Xb  = Vb + SZ;                           // 16 MiB, aliased by Yb
  unsigned short* Yb  = Xb;                                // attn writes after gemm0 reads
  unsigned short* WqT = Xb + SZ;                           // 6 MiB
  unsigned short* WoT = WqT + (size_t)3*D_MODEL*D_MODEL;   // 2 MiB

  prep_kernel<<<dim3(4096 + 768 + 256), 256, 0, stream>>>(
      x, Xb, w_qkv, WqT, w_out, WoT);

  gemm_db<0><<<dim3(3*D_MODEL/128, BATCH*SEQ/128), 256, 0, stream>>>(
      Xb, WqT, b_qkv, Qb, Kb, Vb, nullptr);
  attn_kernel<<<dim3(BATCH*NHEADS, 16), 256, 0, stream>>>(Qb, Kb, Vb, Yb);
  gemm_db<1><<<dim3(D_MODEL/128, BATCH*SEQ/128), 256, 0, stream>>>(
      Yb, WoT, b_out, nullptr, nullptr, nullptr, out);
}